// Round 5
// baseline (248.781 us; speedup 1.0000x reference)
//
#include <hip/hip_runtime.h>
#include <math.h>

#define BB 2
#define NN 128
#define DD 128     // DIM
#define DI 256     // H*DH
#define DM 512
#define SS 5
#define SDI 1280   // S*DI
#define HS 40      // H*S
#define M1 3
#define M2 5

typedef __attribute__((ext_vector_type(8))) short bf16x8_t;
typedef __attribute__((ext_vector_type(4))) float f32x4_t;

#define MFMA __builtin_amdgcn_mfma_f32_16x16x32_bf16

__device__ __forceinline__ float sigm(float x){ return __fdividef(1.0f, 1.0f + __expf(-x)); }
__device__ __forceinline__ unsigned short f2bf(float f){
    union { float f; unsigned u; } v; v.f = f;
    unsigned r = v.u + 0x7FFFu + ((v.u>>16)&1u);   // RNE
    return (unsigned short)(r>>16);
}
__device__ __forceinline__ unsigned pk2(float a, float b){
    return (unsigned)f2bf(a) | ((unsigned)f2bf(b)<<16);
}
__device__ __forceinline__ float bflo(unsigned u){ union{unsigned u; float f;} v; v.u = u<<16; return v.f; }
__device__ __forceinline__ float bfhi(unsigned u){ union{unsigned u; float f;} v; v.u = u & 0xFFFF0000u; return v.f; }

// ---------------------------------------------------------------------------
// prep: tiled f32->bf16 transposes of Wv2/Wpv2/Wek/Wev/Wo; WnT gather; LN.
// ---------------------------------------------------------------------------
__global__ __launch_bounds__(256) void prep(
    const float* __restrict__ h,
    const float* __restrict__ g_hi, const float* __restrict__ g_hj,
    const float* __restrict__ Wq, const float* __restrict__ Wk,
    const float* __restrict__ Wv1, const float* __restrict__ Wpv1,
    const float* __restrict__ Wg,
    const float* __restrict__ Wek, const float* __restrict__ Wev,
    const float* __restrict__ Wo, const float* __restrict__ Wv2,
    const float* __restrict__ Wpv2,
    unsigned short* __restrict__ hi_ws, unsigned short* __restrict__ hj_ws,
    unsigned short* __restrict__ WekT, unsigned short* __restrict__ WevT,
    unsigned short* __restrict__ WoT, unsigned short* __restrict__ W2T,
    unsigned short* __restrict__ WnT)
{
    const int bx = blockIdx.x, tid = threadIdx.x;
    __shared__ unsigned short sLT[64*65];
    if (bx < 408){
        const float* src; unsigned short* dst; int W, ldD, R0, C0;
        int t = bx;
        if (t < 160){ src=Wv2;  dst=W2T;            W=SDI; ldD=DM;  R0=(t%20)*64; C0=(t/20)*64; }
        else if (t < 320){ t-=160; src=Wpv2; dst=W2T + SDI*DM; W=SDI; ldD=DM; R0=(t%20)*64; C0=(t/20)*64; }
        else if (t < 360){ t-=320; src=Wek; dst=WekT; W=SDI; ldD=DD; R0=(t%20)*64; C0=(t/20)*64; }
        else if (t < 400){ t-=360; src=Wev; dst=WevT; W=SDI; ldD=DD; R0=(t%20)*64; C0=(t/20)*64; }
        else { t-=400; src=Wo; dst=WoT; W=DD; ldD=DI; R0=(t%2)*64; C0=(t/2)*64; }
        const int tx = tid & 63, ty = tid >> 6;
        #pragma unroll
        for (int k=0;k<16;++k){
            int c = C0 + 4*k + ty;
            sLT[tx*65 + 4*k + ty] = f2bf(src[(size_t)c*W + R0 + tx]);
        }
        __syncthreads();
        #pragma unroll
        for (int k=0;k<16;++k){
            int rr = 4*k + ty;
            dst[(size_t)(R0+rr)*ldD + C0 + tx] = sLT[rr*65 + tx];
        }
    } else {
        const int node = bx - 408;
        if (tid < 64){
            float h0 = h[node*DD + tid], h1 = h[node*DD + 64 + tid];
            float s1 = h0 + h1, s2 = h0*h0 + h1*h1;
            #pragma unroll
            for (int off=32; off; off>>=1){ s1 += __shfl_xor(s1,off); s2 += __shfl_xor(s2,off); }
            float mu   = s1*(1.0f/DD);
            float var  = s2*(1.0f/DD) - mu*mu;
            float rstd = rsqrtf(var + 1e-5f);
            float c0 = (h0-mu)*rstd, c1 = (h1-mu)*rstd;
            hi_ws[node*DD + tid]      = f2bf(c0*g_hi[tid]);
            hi_ws[node*DD + 64 + tid] = f2bf(c1*g_hi[64+tid]);
            hj_ws[node*DD + tid]      = f2bf(c0*g_hj[tid]);
            hj_ws[node*DD + 64 + tid] = f2bf(c1*g_hj[64+tid]);
        }
        // WnT rows: 0..255 Wq | 256..303 Wg(40)+pad | 304..559 Wk | 560..1071 Wv1 | 1072..1583 Wpv1
        for (int f = node*256 + tid; f < 1584*DD; f += 256*256){
            int row = f >> 7, d = f & 127;
            float v;
            if (row < 256)       v = Wq[d*DI + row];
            else if (row < 304){ int c = row-256; v = (c < HS) ? Wg[d*HS + c] : 0.0f; }
            else if (row < 560)  v = Wk[d*DI + (row-304)];
            else if (row < 1072) v = Wv1[d*DM + (row-560)];
            else                 v = Wpv1[d*DM + (row-1072)];
            WnT[f] = f2bf(v);
        }
    }
}

// ---------------------------------------------------------------------------
// node_gemm: [cols 1584] x [256 nodes] = WnT @ (hi|hj)^T via MFMA.
// ---------------------------------------------------------------------------
__global__ __launch_bounds__(256,4) void node_gemm(
    const unsigned short* __restrict__ WnT,
    const unsigned short* __restrict__ hi_ws, const unsigned short* __restrict__ hj_ws,
    const float* __restrict__ bg, const float* __restrict__ bv1, const float* __restrict__ bpv1,
    float* __restrict__ q_ws, float* __restrict__ k_ws,
    float* __restrict__ g_ws, unsigned short* __restrict__ hid_ws)
{
    const int bx = blockIdx.x;
    const int tile = bx % 99, nq = bx / 99;
    const int tid = threadIdx.x, lane = tid&63, w = tid>>6;
    const int l15 = lane&15, g4 = lane>>4;
    const int ntile = nq*4 + w;
    const unsigned short* A  = WnT + (size_t)(tile*16 + l15)*DD + 8*g4;
    const unsigned short* Bp = ((tile < 19) ? hi_ws : hj_ws) + (size_t)(ntile*16 + l15)*DD + 8*g4;
    f32x4_t c = {0.f,0.f,0.f,0.f};
    #pragma unroll
    for (int ks=0; ks<4; ++ks)
        c = MFMA(*(const bf16x8_t*)(A + 32*ks), *(const bf16x8_t*)(Bp + 32*ks), c, 0,0,0);
    const int node = ntile*16 + l15;
    const int col0 = tile*16 + 4*g4;
    if (tile < 16){
        f32x4_t* dst = (f32x4_t*)(q_ws + (size_t)node*DI + col0);
        *dst = c;
    } else if (tile < 19){
        #pragma unroll
        for (int r=0;r<4;++r){
            int cc = col0 + r - 256;
            if (cc < HS) g_ws[node*HS + cc] = sigm(c[r] + bg[cc]);
        }
    } else if (tile < 35){
        f32x4_t* dst = (f32x4_t*)(k_ws + (size_t)node*DI + (col0-304));
        *dst = c;
    } else if (tile < 67){
        int cc = col0 - 560;
        float s0 = c[0]+bv1[cc], s1 = c[1]+bv1[cc+1], s2 = c[2]+bv1[cc+2], s3 = c[3]+bv1[cc+3];
        s0 *= sigm(s0); s1 *= sigm(s1); s2 *= sigm(s2); s3 *= sigm(s3);
        uint2 pkk; pkk.x = pk2(s0,s1); pkk.y = pk2(s2,s3);
        *(uint2*)(hid_ws + (size_t)node*1024 + cc) = pkk;
    } else {
        int cc = col0 - 1072;
        float s0 = c[0]+bpv1[cc], s1 = c[1]+bpv1[cc+1], s2 = c[2]+bpv1[cc+2], s3 = c[3]+bpv1[cc+3];
        s0 *= sigm(s0); s1 *= sigm(s1); s2 *= sigm(s2); s3 *= sigm(s3);
        uint2 pkk; pkk.x = pk2(s0,s1); pkk.y = pk2(s2,s3);
        *(uint2*)(hid_ws + (size_t)node*1024 + 512 + cc) = pkk;
    }
}

// ---------------------------------------------------------------------------
// v2_gemm: vpv[node][2560] = W2T @ hid^T (+bias), bf16 out.
// ---------------------------------------------------------------------------
__global__ __launch_bounds__(256,4) void v2_gemm(
    const unsigned short* __restrict__ W2T,
    const unsigned short* __restrict__ hid_ws,
    const float* __restrict__ bv2, const float* __restrict__ bpv2,
    unsigned short* __restrict__ vpv_ws)
{
    const int bx = blockIdx.x;
    const int otile = bx % 160, nq = bx / 160;
    const int tid = threadIdx.x, lane = tid&63, w = tid>>6;
    const int l15 = lane&15, g4 = lane>>4;
    const int ntile = nq*4 + w;
    const int obase = otile*16;
    const int koff = (obase < SDI) ? 0 : 512;
    const unsigned short* A  = W2T + (size_t)(obase + l15)*DM + 8*g4;
    const unsigned short* Bp = hid_ws + (size_t)(ntile*16 + l15)*1024 + koff + 8*g4;
    f32x4_t c = {0.f,0.f,0.f,0.f};
    #pragma unroll
    for (int ks=0; ks<16; ++ks)
        c = MFMA(*(const bf16x8_t*)(A + 32*ks), *(const bf16x8_t*)(Bp + 32*ks), c, 0,0,0);
    const int node = ntile*16 + l15;
    const int o0 = obase + 4*g4;
    const float* bias = (obase < SDI) ? bv2 : bpv2;
    const int ob = (obase < SDI) ? o0 : (o0 - SDI);
    float v0 = c[0]+bias[ob], v1 = c[1]+bias[ob+1], v2 = c[2]+bias[ob+2], v3 = c[3]+bias[ob+3];
    uint2 pkk; pkk.x = pk2(v0,v1); pkk.y = pk2(v2,v3);
    *(uint2*)(vpv_ws + (size_t)node*2560 + o0) = pkk;
}

// ---------------------------------------------------------------------------
// sim_kernel: sim[j,h,s] = sum_dh QK[j,dh]*silu(ek[j,dh]) per (node, j-quarter).
// grid 1024 = 256 nodes x 4 quarters; 256 thr = 4 waves.
// LDS: sQK @0 (16KB), sT @16384 (8KB, overlaid by sSIM), sQf @24576.
// ---------------------------------------------------------------------------
__global__ __launch_bounds__(256,4) void sim_kernel(
    const float* __restrict__ t_ij,
    const unsigned short* __restrict__ WekT,
    const float* __restrict__ q_ws, const float* __restrict__ k_ws,
    float* __restrict__ sim_ws)
{
    __shared__ __align__(16) char sm[25600];
    float* sSIM = (float*)(sm + 16384);
    float* sQf  = (float*)(sm + 24576);

    const int bx = blockIdx.x;
    const int node = bx >> 2, qt = bx & 3;
    const int b = node >> 7;
    const int j0 = qt*32;
    const int tid = threadIdx.x, lane = tid&63, w = tid>>6;
    const int l15 = lane&15, g4 = lane>>4;

    sQf[tid] = q_ws[(size_t)node*DI + tid];
    {   // stage T (32 rows) -> bf16 swizzled @16384
        const int j = tid>>3, seg = tid&7;
        const float* src = t_ij + (size_t)(node*NN + j0 + j)*DD + seg*16;
        char* row = sm + 16384 + j*256;
        const int swz = (j&7)<<4;
        #pragma unroll
        for (int u=0;u<4;++u){
            float4 tv = *(const float4*)(src + 4*u);
            uint2 pkk; pkk.x = pk2(tv.x,tv.y); pkk.y = pk2(tv.z,tv.w);
            *(uint2*)(row + ((2*(seg*16+4*u)) ^ swz)) = pkk;
        }
    }
    __syncthreads();
    {   // QK build -> bf16 swizzled @0
        const int j = tid>>3, seg = tid&7;
        const float* kr = k_ws + (size_t)(b*NN + j0 + j)*DI + seg*32;
        char* row = sm + j*512;
        const int swz = (j&7)<<4;
        #pragma unroll
        for (int u=0;u<8;++u){
            float4 kv = *(const float4*)(kr + 4*u);
            const float* qv = sQf + seg*32 + 4*u;
            uint2 pkk; pkk.x = pk2(kv.x*qv[0], kv.y*qv[1]); pkk.y = pk2(kv.z*qv[2], kv.w*qv[3]);
            *(uint2*)(row + ((2*(seg*32+4*u)) ^ swz)) = pkk;
        }
    }
    bf16x8_t bT[2][4];
    #pragma unroll
    for (int jt=0; jt<2; ++jt){
        const int jc = jt*16 + l15;
        const char* row = sm + 16384 + jc*256;
        const int swz = (jc&7)<<4;
        #pragma unroll
        for (int ks=0; ks<4; ++ks)
            bT[jt][ks] = *(const bf16x8_t*)(row + ((2*(32*ks + 8*g4)) ^ swz));
    }
    __syncthreads();   // QK ready; bT reads done before sSIM overlays sT

    const unsigned short* Wbase = WekT + (size_t)l15*DD + 8*g4;
    for (int p8=0; p8<10; ++p8){
        const int p = 4*p8 + w;            // m-pair index (32 cols = one (h,s))
        const unsigned short* ap = Wbase + (size_t)(2*p)*16*DD;
        bf16x8_t a0[4], a1[4];
        #pragma unroll
        for (int ks=0;ks<4;++ks){
            a0[ks] = *(const bf16x8_t*)(ap + 32*ks);
            a1[ks] = *(const bf16x8_t*)(ap + 2048 + 32*ks);
        }
        const int hs = (p&7)*SS + (p>>3);
        const int o0 = 32*p + 4*g4;
        const int qk0 = o0 & 255;          // ek col -> QK elem (mod DI)
        #pragma unroll
        for (int jt=0; jt<2; ++jt){
            f32x4_t c0 = {0.f,0.f,0.f,0.f}, c1 = {0.f,0.f,0.f,0.f};
            #pragma unroll
            for (int ks=0; ks<4; ++ks){
                c0 = MFMA(a0[ks], bT[jt][ks], c0, 0,0,0);
                c1 = MFMA(a1[ks], bT[jt][ks], c1, 0,0,0);
            }
            const int jr = jt*16 + l15;
            const char* qrow = sm + jr*512;
            const int swz = (jr&7)<<4;
            uint2 u0 = *(const uint2*)(qrow + ((2*qk0) ^ swz));
            uint2 u1 = *(const uint2*)(qrow + ((2*(qk0+16)) ^ swz));
            float part =
                (c0[0]*sigm(c0[0]))*bflo(u0.x) + (c0[1]*sigm(c0[1]))*bfhi(u0.x)
              + (c0[2]*sigm(c0[2]))*bflo(u0.y) + (c0[3]*sigm(c0[3]))*bfhi(u0.y)
              + (c1[0]*sigm(c1[0]))*bflo(u1.x) + (c1[1]*sigm(c1[1]))*bfhi(u1.x)
              + (c1[2]*sigm(c1[2]))*bflo(u1.y) + (c1[3]*sigm(c1[3]))*bfhi(u1.y);
            part += __shfl_xor(part, 16);
            part += __shfl_xor(part, 32);
            if (g4 == 0) sSIM[jr*HS + hs] = part;
        }
    }
    __syncthreads();
    {
        float* dst = sim_ws + (size_t)node*NN*HS + j0*HS;
        for (int t2=tid; t2<32*HS; t2+=256) dst[t2] = sSIM[t2];
    }
}

// ---------------------------------------------------------------------------
// softmax_k: in-place softmax over j on sim_ws. grid 256 nodes x 256 thr.
// ---------------------------------------------------------------------------
__global__ __launch_bounds__(256) void softmax_k(float* __restrict__ sim_ws)
{
    const int node = blockIdx.x;
    const int tid = threadIdx.x, lane = tid&63, w = tid>>6;
    float* srow = sim_ws + (size_t)node*NN*HS;
    #pragma unroll
    for (int u=0; u<10; ++u){
        const int hs = w*10 + u;
        float v0 = srow[lane*HS + hs];
        float v1 = srow[(lane+64)*HS + hs];
        float m = fmaxf(v0,v1);
        #pragma unroll
        for (int off=32; off; off>>=1) m = fmaxf(m, __shfl_xor(m,off));
        float e0 = __expf(v0-m), e1 = __expf(v1-m);
        float ssum = e0+e1;
        #pragma unroll
        for (int off=32; off; off>>=1) ssum += __shfl_xor(ssum,off);
        float inv = __fdividef(1.0f, ssum);
        srow[lane*HS + hs]      = e0*inv;
        srow[(lane+64)*HS + hs] = e1*inv;
    }
}

// ---------------------------------------------------------------------------
// out_kernel: ev -> gsea -> @Wo -> j-reduced partials, per (node, j-quarter).
// grid 1024 = 256 nodes x 4 quarters; 512 thr = 8 waves (one d-tile each).
// LDS: sP @0 (16KB, sT overlay in first 8KB), sAT @16384, sG/sR after.
// ---------------------------------------------------------------------------
__global__ __launch_bounds__(512,4) void out_kernel(
    const float* __restrict__ t_ij,
    const unsigned short* __restrict__ WevT, const unsigned short* __restrict__ WoT,
    const unsigned short* __restrict__ vpv_ws,
    const float* __restrict__ g_ws, const float* __restrict__ attn_ws,
    const float* __restrict__ r1, const float* __restrict__ r2,
    const float* __restrict__ x1, const float* __restrict__ x2,
    float* __restrict__ p_ws)
{
    __shared__ __align__(16) char sm[22688];
    float* sAT = (float*)(sm + 16384);   // 32*40 f32
    float* sG  = (float*)(sm + 21504);   // 40
    float* sR1 = (float*)(sm + 21664);   // 96
    float* sR2 = (float*)(sm + 22048);   // 160

    const int bx = blockIdx.x;
    const int node = bx >> 2, qt = bx & 3;
    const int b = node >> 7;
    const int j0 = qt*32;
    const int tid = threadIdx.x, lane = tid&63, w = tid>>6;
    const int l15 = lane&15, g4 = lane>>4;

    {   // stage T (32 rows) @0 (256B rows, swizzled)
        const int j = tid>>4, seg = tid&15;
        const float* src = t_ij + (size_t)(node*NN + j0 + j)*DD + seg*8;
        char* row = sm + j*256;
        const int swz = (j&7)<<4;
        #pragma unroll
        for (int u=0;u<2;++u){
            float4 tv = *(const float4*)(src + 4*u);
            uint2 pkk; pkk.x = pk2(tv.x,tv.y); pkk.y = pk2(tv.z,tv.w);
            *(uint2*)(row + ((2*(seg*8+4*u)) ^ swz)) = pkk;
        }
    }
    {   // attn slice (post-softmax sim_ws)
        const float* asrc = attn_ws + (size_t)node*NN*HS + j0*HS;
        for (int t2=tid; t2<32*HS; t2+=512) sAT[t2] = asrc[t2];
    }
    if (tid < HS) sG[tid] = g_ws[node*HS + tid];
    if (tid < 32*M1) sR1[tid] = r1[((size_t)node*NN + j0)*M1 + tid];
    if (tid < 32*M2) sR2[tid] = r2[((size_t)node*NN + j0)*M2 + tid];
    __syncthreads();

    bf16x8_t bTw[2][4];
    #pragma unroll
    for (int jt=0;jt<2;++jt){
        const int jc = jt*16 + l15;
        const char* row = sm + jc*256;
        const int swz = (jc&7)<<4;
        #pragma unroll
        for (int ks=0;ks<4;++ks)
            bTw[jt][ks] = *(const bf16x8_t*)(row + ((2*(32*ks+8*g4)) ^ swz));
    }
    bf16x8_t bWo[8];
    {
        const unsigned short* wr = WoT + (size_t)(w*16 + l15)*DI + 8*g4;
        #pragma unroll
        for (int ks=0;ks<8;++ks) bWo[ks] = *(const bf16x8_t*)(wr + 32*ks);
    }
    __syncthreads();   // bTw reads done before sP overwrites sT

    const int d = w*16 + l15;
    float ah = 0.f;
    float ax1[M1] = {0.f,0.f,0.f};
    float ax2[M2] = {0.f,0.f,0.f,0.f,0.f};

    for (int s=0; s<SS; ++s){
        // 3a: ev tiles (this wave: m-tiles 2w, 2w+1), gsea -> sP
        #pragma unroll
        for (int mloc=0; mloc<2; ++mloc){
            const int mt = w*2 + mloc;
            const unsigned short* ap = WevT + (size_t)(s*DI + mt*16 + l15)*DD + 8*g4;
            bf16x8_t aa[4];
            #pragma unroll
            for (int ks=0;ks<4;++ks) aa[ks] = *(const bf16x8_t*)(ap + 32*ks);
            const int o4 = mt*16 + 4*g4;
            const int hh = o4 >> 5;
            const float gt = sG[hh*SS + s];
            #pragma unroll
            for (int jt=0;jt<2;++jt){
                const int jloc = jt*16 + l15;
                const unsigned short* vb = vpv_ws + (size_t)(b*NN + j0 + jloc)*2560;
                uint2 vvp = *(const uint2*)(vb + s*DI + o4);
                uint2 pvp = *(const uint2*)(vb + SDI + s*DI + o4);
                const float at = sAT[jloc*HS + hh*SS + s];
                f32x4_t c = {0.f,0.f,0.f,0.f};
                #pragma unroll
                for (int ks=0;ks<4;++ks) c = MFMA(aa[ks], bTw[jt][ks], c, 0,0,0);
                float q0 = (at*bflo(vvp.x) + c[0]*bflo(pvp.x))*gt;
                float q1 = (at*bfhi(vvp.x) + c[1]*bfhi(pvp.x))*gt;
                float q2 = (at*bflo(vvp.y) + c[2]*bflo(pvp.y))*gt;
                float q3 = (at*bfhi(vvp.y) + c[3]*bfhi(pvp.y))*gt;
                uint2 pkk; pkk.x = pk2(q0,q1); pkk.y = pk2(q2,q3);
                *(uint2*)(sm + jloc*512 + ((2*o4) ^ ((jloc&7)<<4))) = pkk;
            }
        }
        __syncthreads();
        // 3b: OUT_s = P @ Wo (this wave: d-tile w), accumulate reductions
        #pragma unroll
        for (int jt=0;jt<2;++jt){
            const int jl = jt*16 + 4*g4;
            float xv[4*M2];
            if (s == 3){
                #pragma unroll
                for (int r=0;r<4;++r){
                    const float* xb = x1 + ((size_t)(b*NN + j0 + jl + r)*DD + d)*M1;
                    #pragma unroll
                    for (int m=0;m<M1;++m) xv[r*M1+m] = xb[m];
                }
            } else if (s == 4){
                #pragma unroll
                for (int r=0;r<4;++r){
                    const float* xb = x2 + ((size_t)(b*NN + j0 + jl + r)*DD + d)*M2;
                    #pragma unroll
                    for (int m=0;m<M2;++m) xv[r*M2+m] = xb[m];
                }
            }
            const int arow = jt*16 + l15;
            const char* pb = sm + arow*512;
            const int aswz = (arow&7)<<4;
            f32x4_t c = {0.f,0.f,0.f,0.f};
            #pragma unroll
            for (int ks=0;ks<8;++ks){
                bf16x8_t a = *(const bf16x8_t*)(pb + ((64*ks + 16*g4) ^ aswz));
                c = MFMA(a, bWo[ks], c, 0,0,0);
            }
            if (s == 0){
                ah += c[0]+c[1]+c[2]+c[3];
            } else if (s == 1){
                #pragma unroll
                for (int r=0;r<4;++r){
                    #pragma unroll
                    for (int m=0;m<M1;++m) ax1[m] = fmaf(sR1[(jl+r)*M1+m], c[r], ax1[m]);
                }
            } else if (s == 2){
                #pragma unroll
                for (int r=0;r<4;++r){
                    #pragma unroll
                    for (int m=0;m<M2;++m) ax2[m] = fmaf(sR2[(jl+r)*M2+m], c[r], ax2[m]);
                }
            } else if (s == 3){
                #pragma unroll
                for (int r=0;r<4;++r){
                    #pragma unroll
                    for (int m=0;m<M1;++m) ax1[m] = fmaf(xv[r*M1+m], c[r], ax1[m]);
                }
            } else {
                #pragma unroll
                for (int r=0;r<4;++r){
                    #pragma unroll
                    for (int m=0;m<M2;++m) ax2[m] = fmaf(xv[r*M2+m], c[r], ax2[m]);
                }
            }
        }
        __syncthreads();
    }
    // reduce across g4 groups, write partials
    {
        float v0 = ah;
        float v1 = ax1[0], v2 = ax1[1], v3 = ax1[2];
        float v4 = ax2[0], v5 = ax2[1], v6 = ax2[2], v7 = ax2[3], v8 = ax2[4];
        v0 += __shfl_xor(v0,16); v0 += __shfl_xor(v0,32);
        v1 += __shfl_xor(v1,16); v1 += __shfl_xor(v1,32);
        v2 += __shfl_xor(v2,16); v2 += __shfl_xor(v2,32);
        v3 += __shfl_xor(v3,16); v3 += __shfl_xor(v3,32);
        v4 += __shfl_xor(v4,16); v4 += __shfl_xor(v4,32);
        v5 += __shfl_xor(v5,16); v5 += __shfl_xor(v5,32);
        v6 += __shfl_xor(v6,16); v6 += __shfl_xor(v6,32);
        v7 += __shfl_xor(v7,16); v7 += __shfl_xor(v7,32);
        v8 += __shfl_xor(v8,16); v8 += __shfl_xor(v8,32);
        if (g4 == 0){
            float* pb = p_ws + ((size_t)(qt*256 + node)*9)*DD + d;
            pb[0*DD] = v0;
            pb[1*DD] = v1; pb[2*DD] = v2; pb[3*DD] = v3;
            pb[4*DD] = v4; pb[5*DD] = v5; pb[6*DD] = v6; pb[7*DD] = v7; pb[8*DD] = v8;
        }
    }
}

// ---------------------------------------------------------------------------
// combine: sum the four j-quarter partials, add residual, write outputs.
// ---------------------------------------------------------------------------
__global__ __launch_bounds__(128) void combine(
    const float* __restrict__ h, const float* __restrict__ p_ws,
    float* __restrict__ out_h, float* __restrict__ out_x1, float* __restrict__ out_x2)
{
    const int node = blockIdx.x, d = threadIdx.x;
    const float* p0 = p_ws + ((size_t)(0*256 + node)*9)*DD + d;
    const float* p1 = p_ws + ((size_t)(1*256 + node)*9)*DD + d;
    const float* p2 = p_ws + ((size_t)(2*256 + node)*9)*DD + d;
    const float* p3 = p_ws + ((size_t)(3*256 + node)*9)*DD + d;
    out_h[(size_t)node*DD + d] = h[(size_t)node*DD + d] + p0[0] + p1[0] + p2[0] + p3[0];
    #pragma unroll
    for (int m=0;m<M1;++m)
        out_x1[((size_t)node*DD + d)*M1 + m] =
            p0[(1+m)*DD] + p1[(1+m)*DD] + p2[(1+m)*DD] + p3[(1+m)*DD];
    #pragma unroll
    for (int m=0;m<M2;++m)
        out_x2[((size_t)node*DD + d)*M2 + m] =
            p0[(4+m)*DD] + p1[(4+m)*DD] + p2[(4+m)*DD] + p3[(4+m)*DD];
}

// ---------------------------------------------------------------------------
extern "C" void kernel_launch(void* const* d_in, const int* in_sizes, int n_in,
                              void* d_out, int out_size, void* d_ws, size_t ws_size,
                              hipStream_t stream)
{
    (void)in_sizes; (void)n_in; (void)out_size; (void)ws_size;
    const float* h    = (const float*)d_in[0];
    const float* t_ij = (const float*)d_in[1];
    const float* r1   = (const float*)d_in[2];
    const float* r2   = (const float*)d_in[3];
    const float* x1   = (const float*)d_in[4];
    const float* x2   = (const float*)d_in[5];
    const float* g_hi = (const float*)d_in[6];
    const float* g_hj = (const float*)d_in[7];
    const float* Wq   = (const float*)d_in[8];
    const float* Wk   = (const float*)d_in[9];
    const float* Wv1  = (const float*)d_in[10];
    const float* bv1  = (const float*)d_in[11];
    const float* Wv2  = (const float*)d_in[12];
    const float* bv2  = (const float*)d_in[13];
    const float* Wpv1 = (const float*)d_in[14];
    const float* bpv1 = (const float*)d_in[15];
    const float* Wpv2 = (const float*)d_in[16];
    const float* bpv2 = (const float*)d_in[17];
    const float* Wek  = (const float*)d_in[18];
    const float* Wev  = (const float*)d_in[19];
    const float* Wg   = (const float*)d_in[20];
    const float* bg   = (const float*)d_in[21];
    const float* Wo   = (const float*)d_in[22];

    float* fb     = (float*)d_ws;
    float* q_ws   = fb;                       // 65536
    float* k_ws   = q_ws   + 65536;           // 65536
    float* g_ws   = k_ws   + 65536;           // 10240
    float* sim_ws = g_ws   + 10240;           // 1310720
    float* p_ws   = sim_ws + 1310720;         // 1179648
    unsigned short* hi_ws  = (unsigned short*)(p_ws + 1179648);
    unsigned short* hj_ws  = hi_ws  + 32768;
    unsigned short* hid_ws = hj_ws  + 32768;  // 262144
    unsigned short* vpv_ws = hid_ws + 262144; // 655360
    unsigned short* WekT   = vpv_ws + 655360; // 163840
    unsigned short* WevT   = WekT   + 163840; // 163840
    unsigned short* WoT    = WevT   + 163840; // 32768
    unsigned short* W2T    = WoT    + 32768;  // 1310720
    unsigned short* WnT    = W2T    + 1310720;// 202752

    float* out_h  = (float*)d_out;
    float* out_x1 = out_h  + BB*NN*DD;
    float* out_x2 = out_x1 + BB*NN*DD*M1;

    prep<<<664, 256, 0, stream>>>(h, g_hi, g_hj, Wq, Wk, Wv1, Wpv1, Wg,
        Wek, Wev, Wo, Wv2, Wpv2, hi_ws, hj_ws, WekT, WevT, WoT, W2T, WnT);

    node_gemm<<<396, 256, 0, stream>>>(WnT, hi_ws, hj_ws, bg, bv1, bpv1,
        q_ws, k_ws, g_ws, hid_ws);

    v2_gemm<<<640, 256, 0, stream>>>(W2T, hid_ws, bv2, bpv2, vpv_ws);

    sim_kernel<<<1024, 256, 0, stream>>>(t_ij, WekT, q_ws, k_ws, sim_ws);

    softmax_k<<<256, 256, 0, stream>>>(sim_ws);

    out_kernel<<<1024, 512, 0, stream>>>(t_ij, WevT, WoT, vpv_ws, g_ws, sim_ws,
        r1, r2, x1, x2, p_ws);

    combine<<<256, 128, 0, stream>>>(h, p_ws, out_h, out_x1, out_x2);
}

// Round 6
// 243.764 us; speedup vs baseline: 1.0206x; 1.0206x over previous
//
#include <hip/hip_runtime.h>
#include <math.h>

#define BB 2
#define NN 128
#define DD 128     // DIM
#define DI 256     // H*DH
#define DM 512
#define SS 5
#define SDI 1280   // S*DI
#define HS 40      // H*S
#define M1 3
#define M2 5

typedef __attribute__((ext_vector_type(8))) short bf16x8_t;
typedef __attribute__((ext_vector_type(4))) float f32x4_t;

#define MFMA __builtin_amdgcn_mfma_f32_16x16x32_bf16

__device__ __forceinline__ float sigm(float x){ return __fdividef(1.0f, 1.0f + __expf(-x)); }
__device__ __forceinline__ unsigned short f2bf(float f){
    union { float f; unsigned u; } v; v.f = f;
    unsigned r = v.u + 0x7FFFu + ((v.u>>16)&1u);   // RNE
    return (unsigned short)(r>>16);
}
__device__ __forceinline__ unsigned pk2(float a, float b){
    return (unsigned)f2bf(a) | ((unsigned)f2bf(b)<<16);
}
__device__ __forceinline__ float bflo(unsigned u){ union{unsigned u; float f;} v; v.u = u<<16; return v.f; }
__device__ __forceinline__ float bfhi(unsigned u){ union{unsigned u; float f;} v; v.u = u & 0xFFFF0000u; return v.f; }

// ---------------------------------------------------------------------------
// prep: tiled f32->bf16 transposes of Wv2/Wpv2/Wek/Wev/Wo; WnT gather; LN.
// ---------------------------------------------------------------------------
__global__ __launch_bounds__(256) void prep(
    const float* __restrict__ h,
    const float* __restrict__ g_hi, const float* __restrict__ g_hj,
    const float* __restrict__ Wq, const float* __restrict__ Wk,
    const float* __restrict__ Wv1, const float* __restrict__ Wpv1,
    const float* __restrict__ Wg,
    const float* __restrict__ Wek, const float* __restrict__ Wev,
    const float* __restrict__ Wo, const float* __restrict__ Wv2,
    const float* __restrict__ Wpv2,
    unsigned short* __restrict__ hi_ws, unsigned short* __restrict__ hj_ws,
    unsigned short* __restrict__ WekT, unsigned short* __restrict__ WevT,
    unsigned short* __restrict__ WoT, unsigned short* __restrict__ W2T,
    unsigned short* __restrict__ WnT)
{
    const int bx = blockIdx.x, tid = threadIdx.x;
    __shared__ unsigned short sLT[64*65];
    if (bx < 408){
        const float* src; unsigned short* dst; int W, ldD, R0, C0;
        int t = bx;
        if (t < 160){ src=Wv2;  dst=W2T;            W=SDI; ldD=DM;  R0=(t%20)*64; C0=(t/20)*64; }
        else if (t < 320){ t-=160; src=Wpv2; dst=W2T + SDI*DM; W=SDI; ldD=DM; R0=(t%20)*64; C0=(t/20)*64; }
        else if (t < 360){ t-=320; src=Wek; dst=WekT; W=SDI; ldD=DD; R0=(t%20)*64; C0=(t/20)*64; }
        else if (t < 400){ t-=360; src=Wev; dst=WevT; W=SDI; ldD=DD; R0=(t%20)*64; C0=(t/20)*64; }
        else { t-=400; src=Wo; dst=WoT; W=DD; ldD=DI; R0=(t%2)*64; C0=(t/2)*64; }
        const int tx = tid & 63, ty = tid >> 6;
        #pragma unroll
        for (int k=0;k<16;++k){
            int c = C0 + 4*k + ty;
            sLT[tx*65 + 4*k + ty] = f2bf(src[(size_t)c*W + R0 + tx]);
        }
        __syncthreads();
        #pragma unroll
        for (int k=0;k<16;++k){
            int rr = 4*k + ty;
            dst[(size_t)(R0+rr)*ldD + C0 + tx] = sLT[rr*65 + tx];
        }
    } else {
        const int node = bx - 408;
        if (tid < 64){
            float h0 = h[node*DD + tid], h1 = h[node*DD + 64 + tid];
            float s1 = h0 + h1, s2 = h0*h0 + h1*h1;
            #pragma unroll
            for (int off=32; off; off>>=1){ s1 += __shfl_xor(s1,off); s2 += __shfl_xor(s2,off); }
            float mu   = s1*(1.0f/DD);
            float var  = s2*(1.0f/DD) - mu*mu;
            float rstd = rsqrtf(var + 1e-5f);
            float c0 = (h0-mu)*rstd, c1 = (h1-mu)*rstd;
            hi_ws[node*DD + tid]      = f2bf(c0*g_hi[tid]);
            hi_ws[node*DD + 64 + tid] = f2bf(c1*g_hi[64+tid]);
            hj_ws[node*DD + tid]      = f2bf(c0*g_hj[tid]);
            hj_ws[node*DD + 64 + tid] = f2bf(c1*g_hj[64+tid]);
        }
        // WnT rows: 0..255 Wq | 256..303 Wg(40)+pad | 304..559 Wk | 560..1071 Wv1 | 1072..1583 Wpv1
        for (int f = node*256 + tid; f < 1584*DD; f += 256*256){
            int row = f >> 7, d = f & 127;
            float v;
            if (row < 256)       v = Wq[d*DI + row];
            else if (row < 304){ int c = row-256; v = (c < HS) ? Wg[d*HS + c] : 0.0f; }
            else if (row < 560)  v = Wk[d*DI + (row-304)];
            else if (row < 1072) v = Wv1[d*DM + (row-560)];
            else                 v = Wpv1[d*DM + (row-1072)];
            WnT[f] = f2bf(v);
        }
    }
}

// ---------------------------------------------------------------------------
// node_gemm: [cols 1584] x [256 nodes] = WnT @ (hi|hj)^T via MFMA.
// ---------------------------------------------------------------------------
__global__ __launch_bounds__(256,4) void node_gemm(
    const unsigned short* __restrict__ WnT,
    const unsigned short* __restrict__ hi_ws, const unsigned short* __restrict__ hj_ws,
    const float* __restrict__ bg, const float* __restrict__ bv1, const float* __restrict__ bpv1,
    float* __restrict__ q_ws, float* __restrict__ k_ws,
    float* __restrict__ g_ws, unsigned short* __restrict__ hid_ws)
{
    const int bx = blockIdx.x;
    const int tile = bx % 99, nq = bx / 99;
    const int tid = threadIdx.x, lane = tid&63, w = tid>>6;
    const int l15 = lane&15, g4 = lane>>4;
    const int ntile = nq*4 + w;
    const unsigned short* A  = WnT + (size_t)(tile*16 + l15)*DD + 8*g4;
    const unsigned short* Bp = ((tile < 19) ? hi_ws : hj_ws) + (size_t)(ntile*16 + l15)*DD + 8*g4;
    f32x4_t c = {0.f,0.f,0.f,0.f};
    #pragma unroll
    for (int ks=0; ks<4; ++ks)
        c = MFMA(*(const bf16x8_t*)(A + 32*ks), *(const bf16x8_t*)(Bp + 32*ks), c, 0,0,0);
    const int node = ntile*16 + l15;
    const int col0 = tile*16 + 4*g4;
    if (tile < 16){
        f32x4_t* dst = (f32x4_t*)(q_ws + (size_t)node*DI + col0);
        *dst = c;
    } else if (tile < 19){
        #pragma unroll
        for (int r=0;r<4;++r){
            int cc = col0 + r - 256;
            if (cc < HS) g_ws[node*HS + cc] = sigm(c[r] + bg[cc]);
        }
    } else if (tile < 35){
        f32x4_t* dst = (f32x4_t*)(k_ws + (size_t)node*DI + (col0-304));
        *dst = c;
    } else if (tile < 67){
        int cc = col0 - 560;
        float s0 = c[0]+bv1[cc], s1 = c[1]+bv1[cc+1], s2 = c[2]+bv1[cc+2], s3 = c[3]+bv1[cc+3];
        s0 *= sigm(s0); s1 *= sigm(s1); s2 *= sigm(s2); s3 *= sigm(s3);
        uint2 pkk; pkk.x = pk2(s0,s1); pkk.y = pk2(s2,s3);
        *(uint2*)(hid_ws + (size_t)node*1024 + cc) = pkk;
    } else {
        int cc = col0 - 1072;
        float s0 = c[0]+bpv1[cc], s1 = c[1]+bpv1[cc+1], s2 = c[2]+bpv1[cc+2], s3 = c[3]+bpv1[cc+3];
        s0 *= sigm(s0); s1 *= sigm(s1); s2 *= sigm(s2); s3 *= sigm(s3);
        uint2 pkk; pkk.x = pk2(s0,s1); pkk.y = pk2(s2,s3);
        *(uint2*)(hid_ws + (size_t)node*1024 + 512 + cc) = pkk;
    }
}

// ---------------------------------------------------------------------------
// v2_gemm: vpv[node][2560] = W2T @ hid^T (+bias), bf16 out.
// ---------------------------------------------------------------------------
__global__ __launch_bounds__(256,4) void v2_gemm(
    const unsigned short* __restrict__ W2T,
    const unsigned short* __restrict__ hid_ws,
    const float* __restrict__ bv2, const float* __restrict__ bpv2,
    unsigned short* __restrict__ vpv_ws)
{
    const int bx = blockIdx.x;
    const int otile = bx % 160, nq = bx / 160;
    const int tid = threadIdx.x, lane = tid&63, w = tid>>6;
    const int l15 = lane&15, g4 = lane>>4;
    const int ntile = nq*4 + w;
    const int obase = otile*16;
    const int koff = (obase < SDI) ? 0 : 512;
    const unsigned short* A  = W2T + (size_t)(obase + l15)*DM + 8*g4;
    const unsigned short* Bp = hid_ws + (size_t)(ntile*16 + l15)*1024 + koff + 8*g4;
    f32x4_t c = {0.f,0.f,0.f,0.f};
    #pragma unroll
    for (int ks=0; ks<16; ++ks)
        c = MFMA(*(const bf16x8_t*)(A + 32*ks), *(const bf16x8_t*)(Bp + 32*ks), c, 0,0,0);
    const int node = ntile*16 + l15;
    const int o0 = obase + 4*g4;
    const float* bias = (obase < SDI) ? bv2 : bpv2;
    const int ob = (obase < SDI) ? o0 : (o0 - SDI);
    float v0 = c[0]+bias[ob], v1 = c[1]+bias[ob+1], v2 = c[2]+bias[ob+2], v3 = c[3]+bias[ob+3];
    uint2 pkk; pkk.x = pk2(v0,v1); pkk.y = pk2(v2,v3);
    *(uint2*)(vpv_ws + (size_t)node*2560 + o0) = pkk;
}

// ---------------------------------------------------------------------------
// sim_kernel: sim[j,h,s] = sum_dh QK[j,dh]*silu(ek[j,dh]) per (node, j-quarter).
// ---------------------------------------------------------------------------
__global__ __launch_bounds__(256,4) void sim_kernel(
    const float* __restrict__ t_ij,
    const unsigned short* __restrict__ WekT,
    const float* __restrict__ q_ws, const float* __restrict__ k_ws,
    float* __restrict__ sim_ws)
{
    __shared__ __align__(16) char sm[25600];
    float* sSIM = (float*)(sm + 16384);
    float* sQf  = (float*)(sm + 24576);

    const int bx = blockIdx.x;
    const int node = bx >> 2, qt = bx & 3;
    const int b = node >> 7;
    const int j0 = qt*32;
    const int tid = threadIdx.x, lane = tid&63, w = tid>>6;
    const int l15 = lane&15, g4 = lane>>4;

    sQf[tid] = q_ws[(size_t)node*DI + tid];
    {   // stage T (32 rows) -> bf16 swizzled @16384
        const int j = tid>>3, seg = tid&7;
        const float* src = t_ij + (size_t)(node*NN + j0 + j)*DD + seg*16;
        char* row = sm + 16384 + j*256;
        const int swz = (j&7)<<4;
        #pragma unroll
        for (int u=0;u<4;++u){
            float4 tv = *(const float4*)(src + 4*u);
            uint2 pkk; pkk.x = pk2(tv.x,tv.y); pkk.y = pk2(tv.z,tv.w);
            *(uint2*)(row + ((2*(seg*16+4*u)) ^ swz)) = pkk;
        }
    }
    __syncthreads();
    {   // QK build -> bf16 swizzled @0
        const int j = tid>>3, seg = tid&7;
        const float* kr = k_ws + (size_t)(b*NN + j0 + j)*DI + seg*32;
        char* row = sm + j*512;
        const int swz = (j&7)<<4;
        #pragma unroll
        for (int u=0;u<8;++u){
            float4 kv = *(const float4*)(kr + 4*u);
            const float* qv = sQf + seg*32 + 4*u;
            uint2 pkk; pkk.x = pk2(kv.x*qv[0], kv.y*qv[1]); pkk.y = pk2(kv.z*qv[2], kv.w*qv[3]);
            *(uint2*)(row + ((2*(seg*32+4*u)) ^ swz)) = pkk;
        }
    }
    bf16x8_t bT[2][4];
    #pragma unroll
    for (int jt=0; jt<2; ++jt){
        const int jc = jt*16 + l15;
        const char* row = sm + 16384 + jc*256;
        const int swz = (jc&7)<<4;
        #pragma unroll
        for (int ks=0; ks<4; ++ks)
            bT[jt][ks] = *(const bf16x8_t*)(row + ((2*(32*ks + 8*g4)) ^ swz));
    }
    __syncthreads();   // QK ready; bT reads done before sSIM overlays sT

    const unsigned short* Wbase = WekT + (size_t)l15*DD + 8*g4;
    for (int p8=0; p8<10; ++p8){
        const int p = 4*p8 + w;            // m-pair index (32 cols = one (h,s))
        const unsigned short* ap = Wbase + (size_t)(2*p)*16*DD;
        bf16x8_t a0[4], a1[4];
        #pragma unroll
        for (int ks=0;ks<4;++ks){
            a0[ks] = *(const bf16x8_t*)(ap + 32*ks);
            a1[ks] = *(const bf16x8_t*)(ap + 2048 + 32*ks);
        }
        const int hs = (p&7)*SS + (p>>3);
        const int o0 = 32*p + 4*g4;
        const int qk0 = o0 & 255;          // ek col -> QK elem (mod DI)
        #pragma unroll
        for (int jt=0; jt<2; ++jt){
            f32x4_t c0 = {0.f,0.f,0.f,0.f}, c1 = {0.f,0.f,0.f,0.f};
            #pragma unroll
            for (int ks=0; ks<4; ++ks){
                c0 = MFMA(a0[ks], bT[jt][ks], c0, 0,0,0);
                c1 = MFMA(a1[ks], bT[jt][ks], c1, 0,0,0);
            }
            const int jr = jt*16 + l15;
            const char* qrow = sm + jr*512;
            const int swz = (jr&7)<<4;
            uint2 u0 = *(const uint2*)(qrow + ((2*qk0) ^ swz));
            uint2 u1 = *(const uint2*)(qrow + ((2*(qk0+16)) ^ swz));
            float part =
                (c0[0]*sigm(c0[0]))*bflo(u0.x) + (c0[1]*sigm(c0[1]))*bfhi(u0.x)
              + (c0[2]*sigm(c0[2]))*bflo(u0.y) + (c0[3]*sigm(c0[3]))*bfhi(u0.y)
              + (c1[0]*sigm(c1[0]))*bflo(u1.x) + (c1[1]*sigm(c1[1]))*bfhi(u1.x)
              + (c1[2]*sigm(c1[2]))*bflo(u1.y) + (c1[3]*sigm(c1[3]))*bfhi(u1.y);
            part += __shfl_xor(part, 16);
            part += __shfl_xor(part, 32);
            if (g4 == 0) sSIM[jr*HS + hs] = part;
        }
    }
    __syncthreads();
    {
        float* dst = sim_ws + (size_t)node*NN*HS + j0*HS;
        for (int t2=tid; t2<32*HS; t2+=256) dst[t2] = sSIM[t2];
    }
}

// ---------------------------------------------------------------------------
// softmax_k: in-place softmax over j on sim_ws. grid 256 nodes x 256 thr.
// ---------------------------------------------------------------------------
__global__ __launch_bounds__(256) void softmax_k(float* __restrict__ sim_ws)
{
    const int node = blockIdx.x;
    const int tid = threadIdx.x, lane = tid&63, w = tid>>6;
    float* srow = sim_ws + (size_t)node*NN*HS;
    #pragma unroll
    for (int u=0; u<10; ++u){
        const int hs = w*10 + u;
        float v0 = srow[lane*HS + hs];
        float v1 = srow[(lane+64)*HS + hs];
        float m = fmaxf(v0,v1);
        #pragma unroll
        for (int off=32; off; off>>=1) m = fmaxf(m, __shfl_xor(m,off));
        float e0 = __expf(v0-m), e1 = __expf(v1-m);
        float ssum = e0+e1;
        #pragma unroll
        for (int off=32; off; off>>=1) ssum += __shfl_xor(ssum,off);
        float inv = __fdividef(1.0f, ssum);
        srow[lane*HS + hs]      = e0*inv;
        srow[(lane+64)*HS + hs] = e1*inv;
    }
}

// ---------------------------------------------------------------------------
// out_s012: register-only j-contraction for s=0,1,2.
// grid 512 = 256 nodes x 2 j-halves (each block loops 2 quarters); 512 thr.
// LDS: avg @0 (16KB, T staged here at quarter prologue), pvg @16384,
//      sATb @32768 (bf16 32x40), sG @35328.
// p012 out: [jh 2][node 256][m 9][c 256] f32.
// ---------------------------------------------------------------------------
__global__ __launch_bounds__(512,3) void out_s012(
    const float* __restrict__ t_ij,
    const unsigned short* __restrict__ WevT,
    const unsigned short* __restrict__ vpv_ws,
    const float* __restrict__ g_ws, const float* __restrict__ attn_ws,
    const float* __restrict__ r1, const float* __restrict__ r2,
    float* __restrict__ p012)
{
    __shared__ __align__(16) char sm[35488];
    unsigned short* sATb = (unsigned short*)(sm + 32768);
    float* sG = (float*)(sm + 35328);

    const int bx = blockIdx.x;
    const int node = bx >> 1, jh = bx & 1;
    const int b = node >> 7;
    const int tid = threadIdx.x, lane = tid&63, w = tid>>6;
    const int l15 = lane&15, g4 = lane>>4;

    if (tid < HS) sG[tid] = g_ws[node*HS + tid];

    float acc[9][8];
    #pragma unroll
    for (int m=0;m<9;++m)
        #pragma unroll
        for (int t=0;t<8;++t) acc[m][t] = 0.f;

    for (int q2=0; q2<2; ++q2){
        const int j0 = jh*64 + q2*32;
        {   // quarter prologue: stage T (8KB @0) + sATb
            const int j = tid>>4, seg = tid&15;
            const float* src = t_ij + (size_t)(node*NN + j0 + j)*DD + seg*8;
            char* row = sm + j*256;
            const int swz = (j&7)<<4;
            #pragma unroll
            for (int u=0;u<2;++u){
                float4 tv = *(const float4*)(src + 4*u);
                uint2 pkk; pkk.x = pk2(tv.x,tv.y); pkk.y = pk2(tv.z,tv.w);
                *(uint2*)(row + ((2*(seg*8+4*u)) ^ swz)) = pkk;
            }
            const float* asrc = attn_ws + (size_t)node*NN*HS + j0*HS;
            for (int t2=tid; t2<32*HS; t2+=512) sATb[t2] = f2bf(asrc[t2]);
        }
        __syncthreads();
        bf16x8_t bTw[2][4];
        #pragma unroll
        for (int jt=0;jt<2;++jt){
            const int jc = jt*16 + l15;
            const char* row = sm + jc*256;
            const int swz = (jc&7)<<4;
            #pragma unroll
            for (int ks=0;ks<4;++ks)
                bTw[jt][ks] = *(const bf16x8_t*)(row + ((2*(32*ks+8*g4)) ^ swz));
        }
        float r1v[2][M1], r2v[2][M2];
        #pragma unroll
        for (int jt=0;jt<2;++jt){
            const size_t jg = (size_t)node*NN + j0 + jt*16 + l15;
            #pragma unroll
            for (int m=0;m<M1;++m) r1v[jt][m] = r1[jg*M1 + m];
            #pragma unroll
            for (int m=0;m<M2;++m) r2v[jt][m] = r2[jg*M2 + m];
        }
        __syncthreads();

        #pragma unroll
        for (int s=0; s<3; ++s){
            // stage avg = at*gt*v and pvg = gt*pv (coalesced 16B)
            #pragma unroll
            for (int it=0; it<2; ++it){
                const int ch = it*512 + tid;
                const int j = ch>>5, seg = ch&31;
                const int swz = (j&7)<<4;
                const unsigned short* vb = vpv_ws + (size_t)(b*NN+j0+j)*2560 + s*DI + seg*8;
                const int hh = seg>>2;
                const float gt = sG[hh*SS + s];
                const float at = bflo((unsigned)sATb[j*HS + hh*SS + s]);
                const float ag = at * gt;
                uint4 vv = *(const uint4*)vb;
                uint4 pp = *(const uint4*)(vb + SDI);
                uint4 ov, op;
                ov.x = pk2(bflo(vv.x)*ag, bfhi(vv.x)*ag);
                ov.y = pk2(bflo(vv.y)*ag, bfhi(vv.y)*ag);
                ov.z = pk2(bflo(vv.z)*ag, bfhi(vv.z)*ag);
                ov.w = pk2(bflo(vv.w)*ag, bfhi(vv.w)*ag);
                op.x = pk2(bflo(pp.x)*gt, bfhi(pp.x)*gt);
                op.y = pk2(bflo(pp.y)*gt, bfhi(pp.y)*gt);
                op.z = pk2(bflo(pp.z)*gt, bfhi(pp.z)*gt);
                op.w = pk2(bflo(pp.w)*gt, bfhi(pp.w)*gt);
                *(uint4*)(sm + j*512 + ((seg*16) ^ swz)) = ov;
                *(uint4*)(sm + 16384 + j*512 + ((seg*16) ^ swz)) = op;
            }
            __syncthreads();
            // 3a: ev MFMA + gsea + weighted j-accumulate (register-only)
            #pragma unroll
            for (int mloc=0; mloc<2; ++mloc){
                const int mt = w*2 + mloc;
                const unsigned short* ap = WevT + (size_t)(s*DI + mt*16 + l15)*DD + 8*g4;
                bf16x8_t aa[4];
                #pragma unroll
                for (int ks=0;ks<4;++ks) aa[ks] = *(const bf16x8_t*)(ap + 32*ks);
                const int o4 = mt*16 + 4*g4;
                const int t0 = mloc*4;
                #pragma unroll
                for (int jt=0;jt<2;++jt){
                    f32x4_t c = {0.f,0.f,0.f,0.f};
                    #pragma unroll
                    for (int ks=0;ks<4;++ks) c = MFMA(aa[ks], bTw[jt][ks], c, 0,0,0);
                    const int jloc = jt*16 + l15;
                    const int sw2 = (jloc&7)<<4;
                    uint2 av = *(const uint2*)(sm + jloc*512 + ((2*o4) ^ sw2));
                    uint2 pg = *(const uint2*)(sm + 16384 + jloc*512 + ((2*o4) ^ sw2));
                    float g0 = bflo(av.x) + c[0]*bflo(pg.x);
                    float g1 = bfhi(av.x) + c[1]*bfhi(pg.x);
                    float g2 = bflo(av.y) + c[2]*bflo(pg.y);
                    float g3 = bfhi(av.y) + c[3]*bfhi(pg.y);
                    if (s == 0){
                        acc[0][t0+0] += g0; acc[0][t0+1] += g1;
                        acc[0][t0+2] += g2; acc[0][t0+3] += g3;
                    } else if (s == 1){
                        #pragma unroll
                        for (int m=0;m<M1;++m){
                            const float wg = r1v[jt][m];
                            acc[1+m][t0+0] = fmaf(wg, g0, acc[1+m][t0+0]);
                            acc[1+m][t0+1] = fmaf(wg, g1, acc[1+m][t0+1]);
                            acc[1+m][t0+2] = fmaf(wg, g2, acc[1+m][t0+2]);
                            acc[1+m][t0+3] = fmaf(wg, g3, acc[1+m][t0+3]);
                        }
                    } else {
                        #pragma unroll
                        for (int m=0;m<M2;++m){
                            const float wg = r2v[jt][m];
                            acc[4+m][t0+0] = fmaf(wg, g0, acc[4+m][t0+0]);
                            acc[4+m][t0+1] = fmaf(wg, g1, acc[4+m][t0+1]);
                            acc[4+m][t0+2] = fmaf(wg, g2, acc[4+m][t0+2]);
                            acc[4+m][t0+3] = fmaf(wg, g3, acc[4+m][t0+3]);
                        }
                    }
                }
            }
            __syncthreads();
        }
    }
    // reduce over l15 (j) and write
    #pragma unroll
    for (int m=0;m<9;++m)
        #pragma unroll
        for (int t=0;t<8;++t){
            float v = acc[m][t];
            v += __shfl_xor(v,1); v += __shfl_xor(v,2);
            v += __shfl_xor(v,4); v += __shfl_xor(v,8);
            acc[m][t] = v;
        }
    if (l15 == 0){
        float* dst = p012 + ((size_t)(jh*256 + node)*9)*256;
        #pragma unroll
        for (int m=0;m<9;++m)
            #pragma unroll
            for (int t=0;t<8;++t)
                dst[m*256 + (w*2 + (t>>2))*16 + 4*g4 + (t&3)] = acc[m][t];
    }
}

// ---------------------------------------------------------------------------
// out_s34: ev -> gsea -> sP -> @Wo -> x-weighted j-reduction for s=3,4.
// grid 1024 = 256 nodes x 4 quarters; 512 thr = 8 waves.
// LDS: sT/sP @0 (16KB), avg @16384, pvg @32768, sATb @49152, sG @51712.
// p34 out: [qt 4][node 256][row 8][d 128] f32 (rows: x1 m0..2, x2 m0..4)
// ---------------------------------------------------------------------------
__global__ __launch_bounds__(512,3) void out_s34(
    const float* __restrict__ t_ij,
    const unsigned short* __restrict__ WevT, const unsigned short* __restrict__ WoT,
    const unsigned short* __restrict__ vpv_ws,
    const float* __restrict__ g_ws, const float* __restrict__ attn_ws,
    const float* __restrict__ x1, const float* __restrict__ x2,
    float* __restrict__ p34)
{
    __shared__ __align__(16) char sm[51872];
    unsigned short* sATb = (unsigned short*)(sm + 49152);
    float* sG = (float*)(sm + 51712);

    const int bx = blockIdx.x;
    const int node = bx >> 2, qt = bx & 3;
    const int b = node >> 7;
    const int j0 = qt*32;
    const int tid = threadIdx.x, lane = tid&63, w = tid>>6;
    const int l15 = lane&15, g4 = lane>>4;

    if (tid < HS) sG[tid] = g_ws[node*HS + tid];
    {   // stage T (8KB @0) + sATb
        const int j = tid>>4, seg = tid&15;
        const float* src = t_ij + (size_t)(node*NN + j0 + j)*DD + seg*8;
        char* row = sm + j*256;
        const int swz = (j&7)<<4;
        #pragma unroll
        for (int u=0;u<2;++u){
            float4 tv = *(const float4*)(src + 4*u);
            uint2 pkk; pkk.x = pk2(tv.x,tv.y); pkk.y = pk2(tv.z,tv.w);
            *(uint2*)(row + ((2*(seg*8+4*u)) ^ swz)) = pkk;
        }
        const float* asrc = attn_ws + (size_t)node*NN*HS + j0*HS;
        for (int t2=tid; t2<32*HS; t2+=512) sATb[t2] = f2bf(asrc[t2]);
    }
    __syncthreads();
    bf16x8_t bTw[2][4];
    #pragma unroll
    for (int jt=0;jt<2;++jt){
        const int jc = jt*16 + l15;
        const char* row = sm + jc*256;
        const int swz = (jc&7)<<4;
        #pragma unroll
        for (int ks=0;ks<4;++ks)
            bTw[jt][ks] = *(const bf16x8_t*)(row + ((2*(32*ks+8*g4)) ^ swz));
    }
    bf16x8_t bWo[8];
    {
        const unsigned short* wr = WoT + (size_t)(w*16 + l15)*DI + 8*g4;
        #pragma unroll
        for (int ks=0;ks<8;++ks) bWo[ks] = *(const bf16x8_t*)(wr + 32*ks);
    }
    const int d = w*16 + l15;
    float ax1[M1] = {0.f,0.f,0.f};
    float ax2[M2] = {0.f,0.f,0.f,0.f,0.f};

    // ---- macro-ish helpers inline: stage avg/pvg for phase s ----
    #define STAGE_VPV(S) do{                                                   \
        _Pragma("unroll")                                                      \
        for (int it=0; it<2; ++it){                                            \
            const int ch = it*512 + tid;                                       \
            const int j = ch>>5, seg = ch&31;                                  \
            const int swz = (j&7)<<4;                                          \
            const unsigned short* vb = vpv_ws + (size_t)(b*NN+j0+j)*2560 + (S)*DI + seg*8; \
            const int hh = seg>>2;                                             \
            const float gt = sG[hh*SS + (S)];                                  \
            const float at = bflo((unsigned)sATb[j*HS + hh*SS + (S)]);         \
            const float ag = at * gt;                                          \
            uint4 vv = *(const uint4*)vb;                                      \
            uint4 pp = *(const uint4*)(vb + SDI);                              \
            uint4 ov, op;                                                      \
            ov.x = pk2(bflo(vv.x)*ag, bfhi(vv.x)*ag);                          \
            ov.y = pk2(bflo(vv.y)*ag, bfhi(vv.y)*ag);                          \
            ov.z = pk2(bflo(vv.z)*ag, bfhi(vv.z)*ag);                          \
            ov.w = pk2(bflo(vv.w)*ag, bfhi(vv.w)*ag);                          \
            op.x = pk2(bflo(pp.x)*gt, bfhi(pp.x)*gt);                          \
            op.y = pk2(bflo(pp.y)*gt, bfhi(pp.y)*gt);                          \
            op.z = pk2(bflo(pp.z)*gt, bfhi(pp.z)*gt);                          \
            op.w = pk2(bflo(pp.w)*gt, bfhi(pp.w)*gt);                          \
            *(uint4*)(sm + 16384 + j*512 + ((seg*16) ^ swz)) = ov;             \
            *(uint4*)(sm + 32768 + j*512 + ((seg*16) ^ swz)) = op;             \
        }                                                                      \
    } while(0)

    #define PHASE_3A(S) do{                                                    \
        _Pragma("unroll")                                                      \
        for (int mloc=0; mloc<2; ++mloc){                                      \
            const int mt = w*2 + mloc;                                         \
            const unsigned short* ap = WevT + (size_t)((S)*DI + mt*16 + l15)*DD + 8*g4; \
            bf16x8_t aa[4];                                                    \
            _Pragma("unroll")                                                  \
            for (int ks=0;ks<4;++ks) aa[ks] = *(const bf16x8_t*)(ap + 32*ks);  \
            const int o4 = mt*16 + 4*g4;                                       \
            _Pragma("unroll")                                                  \
            for (int jt=0;jt<2;++jt){                                          \
                f32x4_t c = {0.f,0.f,0.f,0.f};                                 \
                _Pragma("unroll")                                              \
                for (int ks=0;ks<4;++ks) c = MFMA(aa[ks], bTw[jt][ks], c, 0,0,0); \
                const int jloc = jt*16 + l15;                                  \
                const int sw2 = (jloc&7)<<4;                                   \
                uint2 av = *(const uint2*)(sm + 16384 + jloc*512 + ((2*o4) ^ sw2)); \
                uint2 pg = *(const uint2*)(sm + 32768 + jloc*512 + ((2*o4) ^ sw2)); \
                float q0 = bflo(av.x) + c[0]*bflo(pg.x);                       \
                float q1 = bfhi(av.x) + c[1]*bfhi(pg.x);                       \
                float q2 = bflo(av.y) + c[2]*bflo(pg.y);                       \
                float q3 = bfhi(av.y) + c[3]*bfhi(pg.y);                       \
                uint2 pkk; pkk.x = pk2(q0,q1); pkk.y = pk2(q2,q3);             \
                *(uint2*)(sm + jloc*512 + ((2*o4) ^ sw2)) = pkk;               \
            }                                                                  \
        }                                                                      \
    } while(0)

    STAGE_VPV(3);
    __syncthreads();          // T-frag reads + stage3 done
    PHASE_3A(3);              // writes sP (overwrites T region; bTw in regs)
    __syncthreads();
    // 3b (s=3, x1) overlapped with stage of s=4
    STAGE_VPV(4);
    #pragma unroll
    for (int jt=0;jt<2;++jt){
        const int jl = jt*16 + 4*g4;
        float xv[4*M1];
        #pragma unroll
        for (int r=0;r<4;++r){
            const float* xb = x1 + ((size_t)(b*NN + j0 + jl + r)*DD + d)*M1;
            #pragma unroll
            for (int m=0;m<M1;++m) xv[r*M1+m] = xb[m];
        }
        const int arow = jt*16 + l15;
        const int aswz = (arow&7)<<4;
        f32x4_t c = {0.f,0.f,0.f,0.f};
        #pragma unroll
        for (int ks=0;ks<8;++ks){
            bf16x8_t a = *(const bf16x8_t*)(sm + arow*512 + ((64*ks + 16*g4) ^ aswz));
            c = MFMA(a, bWo[ks], c, 0,0,0);
        }
        #pragma unroll
        for (int r=0;r<4;++r){
            #pragma unroll
            for (int m=0;m<M1;++m) ax1[m] = fmaf(xv[r*M1+m], c[r], ax1[m]);
        }
    }
    __syncthreads();
    PHASE_3A(4);
    __syncthreads();
    #pragma unroll
    for (int jt=0;jt<2;++jt){
        const int jl = jt*16 + 4*g4;
        float xv[4*M2];
        #pragma unroll
        for (int r=0;r<4;++r){
            const float* xb = x2 + ((size_t)(b*NN + j0 + jl + r)*DD + d)*M2;
            #pragma unroll
            for (int m=0;m<M2;++m) xv[r*M2+m] = xb[m];
        }
        const int arow = jt*16 + l15;
        const int aswz = (arow&7)<<4;
        f32x4_t c = {0.f,0.f,0.f,0.f};
        #pragma unroll
        for (int ks=0;ks<8;++ks){
            bf16x8_t a = *(const bf16x8_t*)(sm + arow*512 + ((64*ks + 16*g4) ^ aswz));
            c = MFMA(a, bWo[ks], c, 0,0,0);
        }
        #pragma unroll
        for (int r=0;r<4;++r){
            #pragma unroll
            for (int m=0;m<M2;++m) ax2[m] = fmaf(xv[r*M2+m], c[r], ax2[m]);
        }
    }
    // reduce across g4, write p34
    {
        float v0 = ax1[0], v1 = ax1[1], v2 = ax1[2];
        float v3 = ax2[0], v4 = ax2[1], v5 = ax2[2], v6 = ax2[3], v7 = ax2[4];
        v0 += __shfl_xor(v0,16); v0 += __shfl_xor(v0,32);
        v1 += __shfl_xor(v1,16); v1 += __shfl_xor(v1,32);
        v2 += __shfl_xor(v2,16); v2 += __shfl_xor(v2,32);
        v3 += __shfl_xor(v3,16); v3 += __shfl_xor(v3,32);
        v4 += __shfl_xor(v4,16); v4 += __shfl_xor(v4,32);
        v5 += __shfl_xor(v5,16); v5 += __shfl_xor(v5,32);
        v6 += __shfl_xor(v6,16); v6 += __shfl_xor(v6,32);
        v7 += __shfl_xor(v7,16); v7 += __shfl_xor(v7,32);
        if (g4 == 0){
            float* pb = p34 + ((size_t)(qt*256 + node)*8)*128 + d;
            pb[0*128] = v0; pb[1*128] = v1; pb[2*128] = v2;
            pb[3*128] = v3; pb[4*128] = v4; pb[5*128] = v5;
            pb[6*128] = v6; pb[7*128] = v7;
        }
    }
    #undef STAGE_VPV
    #undef PHASE_3A
}

// ---------------------------------------------------------------------------
// combine: z = sum(p012 halves); out = z @ Wo + p34 sums + residual.
// grid 256 nodes x 128 thr (thread = output dim d).
// ---------------------------------------------------------------------------
__global__ __launch_bounds__(128) void combine(
    const float* __restrict__ h, const unsigned short* __restrict__ WoT,
    const float* __restrict__ p012, const float* __restrict__ p34,
    float* __restrict__ out_h, float* __restrict__ out_x1, float* __restrict__ out_x2)
{
    __shared__ float sZ[256*12];
    const int node = blockIdx.x, d = threadIdx.x;
    const float* pa = p012 + ((size_t)node*9)*256;
    const float* pb = p012 + ((size_t)(256 + node)*9)*256;
    for (int t=d; t<2304; t+=128){
        int m = t >> 8, c = t & 255;
        sZ[c*12 + m] = pa[t] + pb[t];
    }
    __syncthreads();
    float az[9] = {0.f,0.f,0.f,0.f,0.f,0.f,0.f,0.f,0.f};
    const unsigned short* wr = WoT + (size_t)d*DI;
    for (int cb=0; cb<32; ++cb){
        uint4 wv = *(const uint4*)(wr + cb*8);
        float wk[8];
        wk[0]=bflo(wv.x); wk[1]=bfhi(wv.x); wk[2]=bflo(wv.y); wk[3]=bfhi(wv.y);
        wk[4]=bflo(wv.z); wk[5]=bfhi(wv.z); wk[6]=bflo(wv.w); wk[7]=bfhi(wv.w);
        #pragma unroll
        for (int k=0;k<8;++k){
            const float* zb = sZ + (cb*8+k)*12;
            float4 za = *(const float4*)zb;
            float4 zbv = *(const float4*)(zb+4);
            float z8 = zb[8];
            az[0] = fmaf(za.x,  wk[k], az[0]);
            az[1] = fmaf(za.y,  wk[k], az[1]);
            az[2] = fmaf(za.z,  wk[k], az[2]);
            az[3] = fmaf(za.w,  wk[k], az[3]);
            az[4] = fmaf(zbv.x, wk[k], az[4]);
            az[5] = fmaf(zbv.y, wk[k], az[5]);
            az[6] = fmaf(zbv.z, wk[k], az[6]);
            az[7] = fmaf(zbv.w, wk[k], az[7]);
            az[8] = fmaf(z8,    wk[k], az[8]);
        }
    }
    float p34v[8];
    #pragma unroll
    for (int row=0; row<8; ++row){
        float s = 0.f;
        #pragma unroll
        for (int q=0; q<4; ++q)
            s += p34[((size_t)(q*256 + node)*8 + row)*128 + d];
        p34v[row] = s;
    }
    out_h[(size_t)node*DD + d] = h[(size_t)node*DD + d] + az[0];
    #pragma unroll
    for (int m=0;m<M1;++m)
        out_x1[((size_t)node*DD + d)*M1 + m] = az[1+m] + p34v[m];
    #pragma unroll
    for (int m=0;m<M2;++m)
        out_x2[((size_t)node*DD + d)*M2 + m] = az[4+m] + p34v[3+m];
}

// ---------------------------------------------------------------------------
extern "C" void kernel_launch(void* const* d_in, const int* in_sizes, int n_in,
                              void* d_out, int out_size, void* d_ws, size_t ws_size,
                              hipStream_t stream)
{
    (void)in_sizes; (void)n_in; (void)out_size; (void)ws_size;
    const float* h    = (const float*)d_in[0];
    const float* t_ij = (const float*)d_in[1];
    const float* r1   = (const float*)d_in[2];
    const float* r2   = (const float*)d_in[3];
    const float* x1   = (const float*)d_in[4];
    const float* x2   = (const float*)d_in[5];
    const float* g_hi = (const float*)d_in[6];
    const float* g_hj = (const float*)d_in[7];
    const float* Wq   = (const float*)d_in[8];
    const float* Wk   = (const float*)d_in[9];
    const float* Wv1  = (const float*)d_in[10];
    const float* bv1  = (const float*)d_in[11];
    const float* Wv2  = (const float*)d_in[12];
    const float* bv2  = (const float*)d_in[13];
    const float* Wpv1 = (const float*)d_in[14];
    const float* bpv1 = (const float*)d_in[15];
    const float* Wpv2 = (const float*)d_in[16];
    const float* bpv2 = (const float*)d_in[17];
    const float* Wek  = (const float*)d_in[18];
    const float* Wev  = (const float*)d_in[19];
    const float* Wg   = (const float*)d_in[20];
    const float* bg   = (const float*)d_in[21];
    const float* Wo   = (const float*)d_in[22];

    float* fb     = (float*)d_ws;
    float* q_ws   = fb;                       // 65536
    float* k_ws   = q_ws   + 65536;           // 65536
    float* g_ws   = k_ws   + 65536;           // 10240
    float* sim_ws = g_ws   + 10240;           // 1310720
    float* p012   = sim_ws + 1310720;         // 1179648
    float* p34    = p012   + 1179648;         // 1048576
    unsigned short* hi_ws  = (unsigned short*)(p34 + 1048576);
    unsigned short* hj_ws  = hi_ws  + 32768;
    unsigned short* hid_ws = hj_ws  + 32768;  // 262144
    unsigned short* vpv_ws = hid_ws + 262144; // 655360
    unsigned short* WekT   = vpv_ws + 655360; // 163840
    unsigned short* WevT   = WekT   + 163840; // 163840
    unsigned short* WoT    = WevT   + 163840; // 32768
    unsigned short* W2T    = WoT    + 32768;  // 1310720
    unsigned short* WnT    = W2T    + 1310720;// 202752

    float* out_h  = (float*)d_out;
    float* out_x1 = out_h  + BB*NN*DD;
    float* out_x2 = out_x1 + BB*NN*DD*M1;

    prep<<<664, 256, 0, stream>>>(h, g_hi, g_hj, Wq, Wk, Wv1, Wpv1, Wg,
        Wek, Wev, Wo, Wv2, Wpv2, hi_ws, hj_ws, WekT, WevT, WoT, W2T, WnT);

    node_gemm<<<396, 256, 0, stream>>>(WnT, hi_ws, hj_ws, bg, bv1, bpv1,
        q_ws, k_ws, g_ws, hid_ws);

    v2_gemm<<<640, 256, 0, stream>>>(W2T, hid_ws, bv2, bpv2, vpv_ws);

    sim_kernel<<<1024, 256, 0, stream>>>(t_ij, WekT, q_ws, k_ws, sim_ws);

    softmax_k<<<256, 256, 0, stream>>>(sim_ws);

    out_s012<<<512, 512, 0, stream>>>(t_ij, WevT, vpv_ws, g_ws, sim_ws,
        r1, r2, p012);

    out_s34<<<1024, 512, 0, stream>>>(t_ij, WevT, WoT, vpv_ws, g_ws, sim_ws,
        x1, x2, p34);

    combine<<<256, 128, 0, stream>>>(h, WoT, p012, p34, out_h, out_x1, out_x2);
}

// Round 7
// 227.523 us; speedup vs baseline: 1.0934x; 1.0714x over previous
//
#include <hip/hip_runtime.h>
#include <math.h>

#define BB 2
#define NN 128
#define DD 128     // DIM
#define DI 256     // H*DH
#define DM 512
#define SS 5
#define SDI 1280   // S*DI
#define HS 40      // H*S
#define M1 3
#define M2 5

typedef __attribute__((ext_vector_type(8))) short bf16x8_t;
typedef __attribute__((ext_vector_type(4))) float f32x4_t;

#define MFMA __builtin_amdgcn_mfma_f32_16x16x32_bf16

__device__ __forceinline__ float sigm(float x){ return __fdividef(1.0f, 1.0f + __expf(-x)); }
__device__ __forceinline__ unsigned short f2bf(float f){
    union { float f; unsigned u; } v; v.f = f;
    unsigned r = v.u + 0x7FFFu + ((v.u>>16)&1u);   // RNE
    return (unsigned short)(r>>16);
}
__device__ __forceinline__ unsigned pk2(float a, float b){
    return (unsigned)f2bf(a) | ((unsigned)f2bf(b)<<16);
}
__device__ __forceinline__ float bflo(unsigned u){ union{unsigned u; float f;} v; v.u = u<<16; return v.f; }
__device__ __forceinline__ float bfhi(unsigned u){ union{unsigned u; float f;} v; v.u = u & 0xFFFF0000u; return v.f; }

// ---------------------------------------------------------------------------
// prep: tiled f32->bf16 transposes of Wv2/Wpv2/Wek/Wev/Wo; WnT gather; LN.
// ---------------------------------------------------------------------------
__global__ __launch_bounds__(256) void prep(
    const float* __restrict__ h,
    const float* __restrict__ g_hi, const float* __restrict__ g_hj,
    const float* __restrict__ Wq, const float* __restrict__ Wk,
    const float* __restrict__ Wv1, const float* __restrict__ Wpv1,
    const float* __restrict__ Wg,
    const float* __restrict__ Wek, const float* __restrict__ Wev,
    const float* __restrict__ Wo, const float* __restrict__ Wv2,
    const float* __restrict__ Wpv2,
    unsigned short* __restrict__ hi_ws, unsigned short* __restrict__ hj_ws,
    unsigned short* __restrict__ WekT, unsigned short* __restrict__ WevT,
    unsigned short* __restrict__ WoT, unsigned short* __restrict__ W2T,
    unsigned short* __restrict__ WnT)
{
    const int bx = blockIdx.x, tid = threadIdx.x;
    __shared__ unsigned short sLT[64*65];
    if (bx < 408){
        const float* src; unsigned short* dst; int W, ldD, R0, C0;
        int t = bx;
        if (t < 160){ src=Wv2;  dst=W2T;            W=SDI; ldD=DM;  R0=(t%20)*64; C0=(t/20)*64; }
        else if (t < 320){ t-=160; src=Wpv2; dst=W2T + SDI*DM; W=SDI; ldD=DM; R0=(t%20)*64; C0=(t/20)*64; }
        else if (t < 360){ t-=320; src=Wek; dst=WekT; W=SDI; ldD=DD; R0=(t%20)*64; C0=(t/20)*64; }
        else if (t < 400){ t-=360; src=Wev; dst=WevT; W=SDI; ldD=DD; R0=(t%20)*64; C0=(t/20)*64; }
        else { t-=400; src=Wo; dst=WoT; W=DD; ldD=DI; R0=(t%2)*64; C0=(t/2)*64; }
        const int tx = tid & 63, ty = tid >> 6;
        #pragma unroll
        for (int k=0;k<16;++k){
            int c = C0 + 4*k + ty;
            sLT[tx*65 + 4*k + ty] = f2bf(src[(size_t)c*W + R0 + tx]);
        }
        __syncthreads();
        #pragma unroll
        for (int k=0;k<16;++k){
            int rr = 4*k + ty;
            dst[(size_t)(R0+rr)*ldD + C0 + tx] = sLT[rr*65 + tx];
        }
    } else {
        const int node = bx - 408;
        if (tid < 64){
            float h0 = h[node*DD + tid], h1 = h[node*DD + 64 + tid];
            float s1 = h0 + h1, s2 = h0*h0 + h1*h1;
            #pragma unroll
            for (int off=32; off; off>>=1){ s1 += __shfl_xor(s1,off); s2 += __shfl_xor(s2,off); }
            float mu   = s1*(1.0f/DD);
            float var  = s2*(1.0f/DD) - mu*mu;
            float rstd = rsqrtf(var + 1e-5f);
            float c0 = (h0-mu)*rstd, c1 = (h1-mu)*rstd;
            hi_ws[node*DD + tid]      = f2bf(c0*g_hi[tid]);
            hi_ws[node*DD + 64 + tid] = f2bf(c1*g_hi[64+tid]);
            hj_ws[node*DD + tid]      = f2bf(c0*g_hj[tid]);
            hj_ws[node*DD + 64 + tid] = f2bf(c1*g_hj[64+tid]);
        }
        // WnT rows: 0..255 Wq | 256..303 Wg(40)+pad | 304..559 Wk | 560..1071 Wv1 | 1072..1583 Wpv1
        for (int f = node*256 + tid; f < 1584*DD; f += 256*256){
            int row = f >> 7, d = f & 127;
            float v;
            if (row < 256)       v = Wq[d*DI + row];
            else if (row < 304){ int c = row-256; v = (c < HS) ? Wg[d*HS + c] : 0.0f; }
            else if (row < 560)  v = Wk[d*DI + (row-304)];
            else if (row < 1072) v = Wv1[d*DM + (row-560)];
            else                 v = Wpv1[d*DM + (row-1072)];
            WnT[f] = f2bf(v);
        }
    }
}

// ---------------------------------------------------------------------------
// node_gemm: [cols 1584] x [256 nodes] = WnT @ (hi|hj)^T via MFMA.
// ---------------------------------------------------------------------------
__global__ __launch_bounds__(256,4) void node_gemm(
    const unsigned short* __restrict__ WnT,
    const unsigned short* __restrict__ hi_ws, const unsigned short* __restrict__ hj_ws,
    const float* __restrict__ bg, const float* __restrict__ bv1, const float* __restrict__ bpv1,
    float* __restrict__ q_ws, float* __restrict__ k_ws,
    float* __restrict__ g_ws, unsigned short* __restrict__ hid_ws)
{
    const int bx = blockIdx.x;
    const int tile = bx % 99, nq = bx / 99;
    const int tid = threadIdx.x, lane = tid&63, w = tid>>6;
    const int l15 = lane&15, g4 = lane>>4;
    const int ntile = nq*4 + w;
    const unsigned short* A  = WnT + (size_t)(tile*16 + l15)*DD + 8*g4;
    const unsigned short* Bp = ((tile < 19) ? hi_ws : hj_ws) + (size_t)(ntile*16 + l15)*DD + 8*g4;
    f32x4_t c = {0.f,0.f,0.f,0.f};
    #pragma unroll
    for (int ks=0; ks<4; ++ks)
        c = MFMA(*(const bf16x8_t*)(A + 32*ks), *(const bf16x8_t*)(Bp + 32*ks), c, 0,0,0);
    const int node = ntile*16 + l15;
    const int col0 = tile*16 + 4*g4;
    if (tile < 16){
        f32x4_t* dst = (f32x4_t*)(q_ws + (size_t)node*DI + col0);
        *dst = c;
    } else if (tile < 19){
        #pragma unroll
        for (int r=0;r<4;++r){
            int cc = col0 + r - 256;
            if (cc < HS) g_ws[node*HS + cc] = sigm(c[r] + bg[cc]);
        }
    } else if (tile < 35){
        f32x4_t* dst = (f32x4_t*)(k_ws + (size_t)node*DI + (col0-304));
        *dst = c;
    } else if (tile < 67){
        int cc = col0 - 560;
        float s0 = c[0]+bv1[cc], s1 = c[1]+bv1[cc+1], s2 = c[2]+bv1[cc+2], s3 = c[3]+bv1[cc+3];
        s0 *= sigm(s0); s1 *= sigm(s1); s2 *= sigm(s2); s3 *= sigm(s3);
        uint2 pkk; pkk.x = pk2(s0,s1); pkk.y = pk2(s2,s3);
        *(uint2*)(hid_ws + (size_t)node*1024 + cc) = pkk;
    } else {
        int cc = col0 - 1072;
        float s0 = c[0]+bpv1[cc], s1 = c[1]+bpv1[cc+1], s2 = c[2]+bpv1[cc+2], s3 = c[3]+bpv1[cc+3];
        s0 *= sigm(s0); s1 *= sigm(s1); s2 *= sigm(s2); s3 *= sigm(s3);
        uint2 pkk; pkk.x = pk2(s0,s1); pkk.y = pk2(s2,s3);
        *(uint2*)(hid_ws + (size_t)node*1024 + 512 + cc) = pkk;
    }
}

// ---------------------------------------------------------------------------
// v2_gemm: vpv[node][2560] = W2T @ hid^T (+bias), bf16 out.
// ---------------------------------------------------------------------------
__global__ __launch_bounds__(256,4) void v2_gemm(
    const unsigned short* __restrict__ W2T,
    const unsigned short* __restrict__ hid_ws,
    const float* __restrict__ bv2, const float* __restrict__ bpv2,
    unsigned short* __restrict__ vpv_ws)
{
    const int bx = blockIdx.x;
    const int otile = bx % 160, nq = bx / 160;
    const int tid = threadIdx.x, lane = tid&63, w = tid>>6;
    const int l15 = lane&15, g4 = lane>>4;
    const int ntile = nq*4 + w;
    const int obase = otile*16;
    const int koff = (obase < SDI) ? 0 : 512;
    const unsigned short* A  = W2T + (size_t)(obase + l15)*DM + 8*g4;
    const unsigned short* Bp = hid_ws + (size_t)(ntile*16 + l15)*1024 + koff + 8*g4;
    f32x4_t c = {0.f,0.f,0.f,0.f};
    #pragma unroll
    for (int ks=0; ks<16; ++ks)
        c = MFMA(*(const bf16x8_t*)(A + 32*ks), *(const bf16x8_t*)(Bp + 32*ks), c, 0,0,0);
    const int node = ntile*16 + l15;
    const int o0 = obase + 4*g4;
    const float* bias = (obase < SDI) ? bv2 : bpv2;
    const int ob = (obase < SDI) ? o0 : (o0 - SDI);
    float v0 = c[0]+bias[ob], v1 = c[1]+bias[ob+1], v2 = c[2]+bias[ob+2], v3 = c[3]+bias[ob+3];
    uint2 pkk; pkk.x = pk2(v0,v1); pkk.y = pk2(v2,v3);
    *(uint2*)(vpv_ws + (size_t)node*2560 + o0) = pkk;
}

// ---------------------------------------------------------------------------
// sim_kernel: sim[j,h,s] = sum_dh QK[j,dh]*silu(ek[j,dh]) per (node, j-quarter).
// ---------------------------------------------------------------------------
__global__ __launch_bounds__(256,4) void sim_kernel(
    const float* __restrict__ t_ij,
    const unsigned short* __restrict__ WekT,
    const float* __restrict__ q_ws, const float* __restrict__ k_ws,
    float* __restrict__ sim_ws)
{
    __shared__ __align__(16) char sm[25600];
    float* sSIM = (float*)(sm + 16384);
    float* sQf  = (float*)(sm + 24576);

    const int bx = blockIdx.x;
    const int node = bx >> 2, qt = bx & 3;
    const int b = node >> 7;
    const int j0 = qt*32;
    const int tid = threadIdx.x, lane = tid&63, w = tid>>6;
    const int l15 = lane&15, g4 = lane>>4;

    sQf[tid] = q_ws[(size_t)node*DI + tid];
    {   // stage T (32 rows) -> bf16 swizzled @16384
        const int j = tid>>3, seg = tid&7;
        const float* src = t_ij + (size_t)(node*NN + j0 + j)*DD + seg*16;
        char* row = sm + 16384 + j*256;
        const int swz = (j&7)<<4;
        #pragma unroll
        for (int u=0;u<4;++u){
            float4 tv = *(const float4*)(src + 4*u);
            uint2 pkk; pkk.x = pk2(tv.x,tv.y); pkk.y = pk2(tv.z,tv.w);
            *(uint2*)(row + ((2*(seg*16+4*u)) ^ swz)) = pkk;
        }
    }
    __syncthreads();
    {   // QK build -> bf16 swizzled @0
        const int j = tid>>3, seg = tid&7;
        const float* kr = k_ws + (size_t)(b*NN + j0 + j)*DI + seg*32;
        char* row = sm + j*512;
        const int swz = (j&7)<<4;
        #pragma unroll
        for (int u=0;u<8;++u){
            float4 kv = *(const float4*)(kr + 4*u);
            const float* qv = sQf + seg*32 + 4*u;
            uint2 pkk; pkk.x = pk2(kv.x*qv[0], kv.y*qv[1]); pkk.y = pk2(kv.z*qv[2], kv.w*qv[3]);
            *(uint2*)(row + ((2*(seg*32+4*u)) ^ swz)) = pkk;
        }
    }
    bf16x8_t bT[2][4];
    #pragma unroll
    for (int jt=0; jt<2; ++jt){
        const int jc = jt*16 + l15;
        const char* row = sm + 16384 + jc*256;
        const int swz = (jc&7)<<4;
        #pragma unroll
        for (int ks=0; ks<4; ++ks)
            bT[jt][ks] = *(const bf16x8_t*)(row + ((2*(32*ks + 8*g4)) ^ swz));
    }
    __syncthreads();   // QK ready; bT reads done before sSIM overlays sT

    const unsigned short* Wbase = WekT + (size_t)l15*DD + 8*g4;
    for (int p8=0; p8<10; ++p8){
        const int p = 4*p8 + w;            // m-pair index (32 cols = one (h,s))
        const unsigned short* ap = Wbase + (size_t)(2*p)*16*DD;
        bf16x8_t a0[4], a1[4];
        #pragma unroll
        for (int ks=0;ks<4;++ks){
            a0[ks] = *(const bf16x8_t*)(ap + 32*ks);
            a1[ks] = *(const bf16x8_t*)(ap + 2048 + 32*ks);
        }
        const int hs = (p&7)*SS + (p>>3);
        const int o0 = 32*p + 4*g4;
        const int qk0 = o0 & 255;          // ek col -> QK elem (mod DI)
        #pragma unroll
        for (int jt=0; jt<2; ++jt){
            f32x4_t c0 = {0.f,0.f,0.f,0.f}, c1 = {0.f,0.f,0.f,0.f};
            #pragma unroll
            for (int ks=0; ks<4; ++ks){
                c0 = MFMA(a0[ks], bT[jt][ks], c0, 0,0,0);
                c1 = MFMA(a1[ks], bT[jt][ks], c1, 0,0,0);
            }
            const int jr = jt*16 + l15;
            const char* qrow = sm + jr*512;
            const int swz = (jr&7)<<4;
            uint2 u0 = *(const uint2*)(qrow + ((2*qk0) ^ swz));
            uint2 u1 = *(const uint2*)(qrow + ((2*(qk0+16)) ^ swz));
            float part =
                (c0[0]*sigm(c0[0]))*bflo(u0.x) + (c0[1]*sigm(c0[1]))*bfhi(u0.x)
              + (c0[2]*sigm(c0[2]))*bflo(u0.y) + (c0[3]*sigm(c0[3]))*bfhi(u0.y)
              + (c1[0]*sigm(c1[0]))*bflo(u1.x) + (c1[1]*sigm(c1[1]))*bfhi(u1.x)
              + (c1[2]*sigm(c1[2]))*bflo(u1.y) + (c1[3]*sigm(c1[3]))*bfhi(u1.y);
            part += __shfl_xor(part, 16);
            part += __shfl_xor(part, 32);
            if (g4 == 0) sSIM[jr*HS + hs] = part;
        }
    }
    __syncthreads();
    {
        float* dst = sim_ws + (size_t)node*NN*HS + j0*HS;
        for (int t2=tid; t2<32*HS; t2+=256) dst[t2] = sSIM[t2];
    }
}

// ---------------------------------------------------------------------------
// softmax_k: in-place softmax over j on sim_ws, PRE-SCALED by gate[i,h,s].
// ---------------------------------------------------------------------------
__global__ __launch_bounds__(256) void softmax_k(
    float* __restrict__ sim_ws, const float* __restrict__ g_ws)
{
    const int node = blockIdx.x;
    const int tid = threadIdx.x, lane = tid&63, w = tid>>6;
    float* srow = sim_ws + (size_t)node*NN*HS;
    #pragma unroll
    for (int u=0; u<10; ++u){
        const int hs = w*10 + u;
        const float gt = g_ws[node*HS + hs];
        float v0 = srow[lane*HS + hs];
        float v1 = srow[(lane+64)*HS + hs];
        float m = fmaxf(v0,v1);
        #pragma unroll
        for (int off=32; off; off>>=1) m = fmaxf(m, __shfl_xor(m,off));
        float e0 = __expf(v0-m), e1 = __expf(v1-m);
        float ssum = e0+e1;
        #pragma unroll
        for (int off=32; off; off>>=1) ssum += __shfl_xor(ssum,off);
        float inv = __fdividef(gt, ssum);
        srow[lane*HS + hs]      = e0*inv;
        srow[(lane+64)*HS + hs] = e1*inv;
    }
}

// ---------------------------------------------------------------------------
// out_fused: per (node, j-half, s): two back-to-back MFMA GEMMs.
//   G1: EV[256m x 64j] = Wev_s @ T^T ; gsea on C-frags -> swizzled P (LDS)
//   G2: OUT[64j x 128d] = P @ Wo ; per-s weighted j-reduction -> p_out.
// grid 2560 = (node*2+jh)*5+s ; 512 thr = 8 waves. 2 barriers.
// LDS: sT @0 16KB | sP @16384 32KB | sAT @49152 2KB | sW @51200 1.25KB | sG.
// p_out: [nj 512][2176] f32; offsets s0:0 s1:128 s2:512 s3:1152 s4:1536.
// ---------------------------------------------------------------------------
__global__ __launch_bounds__(512,4) void out_fused(
    const float* __restrict__ t_ij,
    const unsigned short* __restrict__ WevT, const unsigned short* __restrict__ WoT,
    const unsigned short* __restrict__ vpv_ws,
    const float* __restrict__ attn_ws,   // pre-scaled by gate
    const float* __restrict__ g_ws,
    const float* __restrict__ r1, const float* __restrict__ r2,
    const float* __restrict__ x1, const float* __restrict__ x2,
    float* __restrict__ p_out)
{
    __shared__ __align__(16) char sm[52512];
    float* sAT = (float*)(sm + 49152);   // [64 j][8 h] f32 (scaled attn, this s)
    float* sW  = (float*)(sm + 51200);   // [64 j][5] r-weights (s=1,2)
    float* sG  = (float*)(sm + 52480);   // [8 h] gates for this s

    const int bx = blockIdx.x;
    const int s  = bx % 5;
    const int nj = bx / 5;               // node*2 + jh
    const int node = nj >> 1, jh = nj & 1;
    const int b = node >> 7;
    const int j0 = jh*64;
    const int tid = threadIdx.x, lane = tid&63, w = tid>>6;
    const int l15 = lane&15, g4 = lane>>4;

    {   // stage T (64 rows) -> swizzled bf16 @0
        const int j = tid>>3, seg = tid&7;
        const float* src = t_ij + (size_t)(node*NN + j0 + j)*DD + seg*16;
        char* row = sm + j*256;
        const int swz = (j&7)<<4;
        #pragma unroll
        for (int u=0;u<4;++u){
            float4 tv = *(const float4*)(src + 4*u);
            uint2 pkk; pkk.x = pk2(tv.x,tv.y); pkk.y = pk2(tv.z,tv.w);
            *(uint2*)(row + ((2*(seg*16+4*u)) ^ swz)) = pkk;
        }
    }
    {   // scaled attn for this s: [64 j][8 h]
        const int j = tid>>3, hh = tid&7;
        sAT[tid] = attn_ws[(size_t)node*NN*HS + (j0+j)*HS + hh*SS + s];
    }
    if (s == 1){
        if (tid < 64*M1){ int j = tid/M1, m = tid - M1*j;
            sW[j*5+m] = r1[((size_t)node*NN + j0)*M1 + tid]; }
    } else if (s == 2){
        if (tid < 64*M2) sW[tid] = r2[((size_t)node*NN + j0)*M2 + tid];
    }
    if (tid < 8) sG[tid] = g_ws[node*HS + tid*SS + s];
    __syncthreads();

    // ---- GEMM-1: EV tile + gsea -> sP ----
    #pragma unroll
    for (int jt=0; jt<4; ++jt){
        const int jc = jt*16 + l15;          // this lane's j (C-frag col)
        bf16x8_t bT[4];
        {
            const char* row = sm + jc*256;
            const int swz = (jc&7)<<4;
            #pragma unroll
            for (int ks=0;ks<4;++ks)
                bT[ks] = *(const bf16x8_t*)(row + ((2*(32*ks+8*g4)) ^ swz));
        }
        const unsigned short* vb = vpv_ws + (size_t)(b*NN + j0 + jc)*2560 + s*DI;
        const float at = sAT[jc*8 + 0];      // will re-index per mt (h changes)
        (void)at;
        char* prow = sm + 16384 + jc*512;
        const int pswz = (jc&7)<<4;
        #pragma unroll
        for (int mloc=0; mloc<2; ++mloc){
            const int mt = w*2 + mloc;
            const unsigned short* ap = WevT + (size_t)(s*DI + mt*16 + l15)*DD + 8*g4;
            bf16x8_t aa[4];
            #pragma unroll
            for (int ks=0;ks<4;++ks) aa[ks] = *(const bf16x8_t*)(ap + 32*ks);
            f32x4_t c = {0.f,0.f,0.f,0.f};
            #pragma unroll
            for (int ks=0;ks<4;++ks) c = MFMA(aa[ks], bT[ks], c, 0,0,0);
            const int m0 = mt*16 + 4*g4;     // C-frag rows m0..m0+3
            const int hh = mt >> 1;
            const float atv = sAT[jc*8 + hh];
            const float gtv = sG[hh];
            uint2 vv = *(const uint2*)(vb + m0);
            uint2 pp = *(const uint2*)(vb + SDI + m0);
            float q0 = atv*bflo(vv.x) + gtv*c[0]*bflo(pp.x);
            float q1 = atv*bfhi(vv.x) + gtv*c[1]*bfhi(pp.x);
            float q2 = atv*bflo(vv.y) + gtv*c[2]*bflo(pp.y);
            float q3 = atv*bfhi(vv.y) + gtv*c[3]*bfhi(pp.y);
            uint2 pkk; pkk.x = pk2(q0,q1); pkk.y = pk2(q2,q3);
            *(uint2*)(prow + ((2*m0) ^ pswz)) = pkk;
        }
    }
    __syncthreads();

    // ---- GEMM-2: OUT = P @ Wo ; weighted j-reduction ----
    const int d = w*16 + l15;
    bf16x8_t bWo[8];
    {
        const unsigned short* wr = WoT + (size_t)d*DI + 8*g4;
        #pragma unroll
        for (int ks=0;ks<8;++ks) bWo[ks] = *(const bf16x8_t*)(wr + 32*ks);
    }
    float acc[5] = {0.f,0.f,0.f,0.f,0.f};
    #pragma unroll
    for (int jt=0; jt<4; ++jt){
        const int arow = jt*16 + l15;
        const char* pb = sm + 16384 + arow*512;
        const int aswz = (arow&7)<<4;
        f32x4_t c = {0.f,0.f,0.f,0.f};
        #pragma unroll
        for (int ks=0;ks<8;++ks){
            bf16x8_t a = *(const bf16x8_t*)(pb + ((64*ks + 16*g4) ^ aswz));
            c = MFMA(a, bWo[ks], c, 0,0,0);
        }
        // rows of OUT tile: j = jt*16 + 4*g4 + r
        if (s == 0){
            acc[0] += c[0]+c[1]+c[2]+c[3];
        } else if (s == 1){
            #pragma unroll
            for (int r=0;r<4;++r){
                const int jr = jt*16 + 4*g4 + r;
                #pragma unroll
                for (int m=0;m<M1;++m) acc[m] = fmaf(sW[jr*5+m], c[r], acc[m]);
            }
        } else if (s == 2){
            #pragma unroll
            for (int r=0;r<4;++r){
                const int jr = jt*16 + 4*g4 + r;
                #pragma unroll
                for (int m=0;m<M2;++m) acc[m] = fmaf(sW[jr*5+m], c[r], acc[m]);
            }
        } else if (s == 3){
            #pragma unroll
            for (int r=0;r<4;++r){
                const int jr = jt*16 + 4*g4 + r;
                const float* xb = x1 + ((size_t)(b*NN + j0 + jr)*DD + d)*M1;
                #pragma unroll
                for (int m=0;m<M1;++m) acc[m] = fmaf(xb[m], c[r], acc[m]);
            }
        } else {
            #pragma unroll
            for (int r=0;r<4;++r){
                const int jr = jt*16 + 4*g4 + r;
                const float* xb = x2 + ((size_t)(b*NN + j0 + jr)*DD + d)*M2;
                #pragma unroll
                for (int m=0;m<M2;++m) acc[m] = fmaf(xb[m], c[r], acc[m]);
            }
        }
    }
    // reduce over g4 (j groups) and store this block's partial slice
    const int NM = (s==0) ? 1 : ((s==1 || s==3) ? M1 : M2);
    const int OFF = (s==0) ? 0 : (s==1) ? 128 : (s==2) ? 512 : (s==3) ? 1152 : 1536;
    #pragma unroll
    for (int m=0;m<5;++m){
        if (m < NM){
            float v = acc[m];
            v += __shfl_xor(v,16); v += __shfl_xor(v,32);
            if (g4 == 0) p_out[(size_t)nj*2176 + OFF + m*DD + d] = v;
        }
    }
}

// ---------------------------------------------------------------------------
// combine: sum the two j-half partials per s-group, add residual.
// ---------------------------------------------------------------------------
__global__ __launch_bounds__(128) void combine(
    const float* __restrict__ h, const float* __restrict__ p_out,
    float* __restrict__ out_h, float* __restrict__ out_x1, float* __restrict__ out_x2)
{
    const int node = blockIdx.x, d = threadIdx.x;
    const float* pa = p_out + (size_t)(node*2+0)*2176;
    const float* pb = p_out + (size_t)(node*2+1)*2176;
    out_h[(size_t)node*DD + d] = h[(size_t)node*DD + d] + pa[d] + pb[d];
    #pragma unroll
    for (int m=0;m<M1;++m)
        out_x1[((size_t)node*DD + d)*M1 + m] =
            pa[128 + m*DD + d] + pb[128 + m*DD + d] +
            pa[1152 + m*DD + d] + pb[1152 + m*DD + d];
    #pragma unroll
    for (int m=0;m<M2;++m)
        out_x2[((size_t)node*DD + d)*M2 + m] =
            pa[512 + m*DD + d] + pb[512 + m*DD + d] +
            pa[1536 + m*DD + d] + pb[1536 + m*DD + d];
}

// ---------------------------------------------------------------------------
extern "C" void kernel_launch(void* const* d_in, const int* in_sizes, int n_in,
                              void* d_out, int out_size, void* d_ws, size_t ws_size,
                              hipStream_t stream)
{
    (void)in_sizes; (void)n_in; (void)out_size; (void)ws_size;
    const float* h    = (const float*)d_in[0];
    const float* t_ij = (const float*)d_in[1];
    const float* r1   = (const float*)d_in[2];
    const float* r2   = (const float*)d_in[3];
    const float* x1   = (const float*)d_in[4];
    const float* x2   = (const float*)d_in[5];
    const float* g_hi = (const float*)d_in[6];
    const float* g_hj = (const float*)d_in[7];
    const float* Wq   = (const float*)d_in[8];
    const float* Wk   = (const float*)d_in[9];
    const float* Wv1  = (const float*)d_in[10];
    const float* bv1  = (const float*)d_in[11];
    const float* Wv2  = (const float*)d_in[12];
    const float* bv2  = (const float*)d_in[13];
    const float* Wpv1 = (const float*)d_in[14];
    const float* bpv1 = (const float*)d_in[15];
    const float* Wpv2 = (const float*)d_in[16];
    const float* bpv2 = (const float*)d_in[17];
    const float* Wek  = (const float*)d_in[18];
    const float* Wev  = (const float*)d_in[19];
    const float* Wg   = (const float*)d_in[20];
    const float* bg   = (const float*)d_in[21];
    const float* Wo   = (const float*)d_in[22];

    float* fb     = (float*)d_ws;
    float* q_ws   = fb;                       // 65536
    float* k_ws   = q_ws   + 65536;           // 65536
    float* g_ws   = k_ws   + 65536;           // 10240
    float* sim_ws = g_ws   + 10240;           // 1310720
    float* p_out  = sim_ws + 1310720;         // 1114112
    unsigned short* hi_ws  = (unsigned short*)(p_out + 1114112);
    unsigned short* hj_ws  = hi_ws  + 32768;
    unsigned short* hid_ws = hj_ws  + 32768;  // 262144
    unsigned short* vpv_ws = hid_ws + 262144; // 655360
    unsigned short* WekT   = vpv_ws + 655360; // 163840
    unsigned short* WevT   = WekT   + 163840; // 163840
    unsigned short* WoT    = WevT   + 163840; // 32768
    unsigned short* W2T    = WoT    + 32768;  // 1310720
    unsigned short* WnT    = W2T    + 1310720;// 202752

    float* out_h  = (float*)d_out;
    float* out_x1 = out_h  + BB*NN*DD;
    float* out_x2 = out_x1 + BB*NN*DD*M1;

    prep<<<664, 256, 0, stream>>>(h, g_hi, g_hj, Wq, Wk, Wv1, Wpv1, Wg,
        Wek, Wev, Wo, Wv2, Wpv2, hi_ws, hj_ws, WekT, WevT, WoT, W2T, WnT);

    node_gemm<<<396, 256, 0, stream>>>(WnT, hi_ws, hj_ws, bg, bv1, bpv1,
        q_ws, k_ws, g_ws, hid_ws);

    v2_gemm<<<640, 256, 0, stream>>>(W2T, hid_ws, bv2, bpv2, vpv_ws);

    sim_kernel<<<1024, 256, 0, stream>>>(t_ij, WekT, q_ws, k_ws, sim_ws);

    softmax_k<<<256, 256, 0, stream>>>(sim_ws, g_ws);

    out_fused<<<2560, 512, 0, stream>>>(t_ij, WevT, WoT, vpv_ws, sim_ws, g_ws,
        r1, r2, x1, x2, p_out);

    combine<<<256, 128, 0, stream>>>(h, p_out, out_h, out_x1, out_x2);
}

// Round 8
// 189.064 us; speedup vs baseline: 1.3159x; 1.2034x over previous
//
#include <hip/hip_runtime.h>
#include <math.h>

#define BB 2
#define NN 128
#define DD 128     // DIM
#define DI 256     // H*DH
#define DM 512
#define SS 5
#define SDI 1280   // S*DI
#define HS 40      // H*S
#define M1 3
#define M2 5

typedef __attribute__((ext_vector_type(8))) short bf16x8_t;
typedef __attribute__((ext_vector_type(4))) float f32x4_t;

#define MFMA __builtin_amdgcn_mfma_f32_16x16x32_bf16

__device__ __forceinline__ float sigm(float x){ return __fdividef(1.0f, 1.0f + __expf(-x)); }
__device__ __forceinline__ unsigned short f2bf(float f){
    union { float f; unsigned u; } v; v.f = f;
    unsigned r = v.u + 0x7FFFu + ((v.u>>16)&1u);   // RNE
    return (unsigned short)(r>>16);
}
__device__ __forceinline__ unsigned pk2(float a, float b){
    return (unsigned)f2bf(a) | ((unsigned)f2bf(b)<<16);
}
__device__ __forceinline__ float bflo(unsigned u){ union{unsigned u; float f;} v; v.u = u<<16; return v.f; }
__device__ __forceinline__ float bfhi(unsigned u){ union{unsigned u; float f;} v; v.u = u & 0xFFFF0000u; return v.f; }

// ---------------------------------------------------------------------------
// prep: tiled f32->bf16 transposes of Wv2/Wpv2/Wek/Wev/Wo; WnT gather; LN.
// ---------------------------------------------------------------------------
__global__ __launch_bounds__(256) void prep(
    const float* __restrict__ h,
    const float* __restrict__ g_hi, const float* __restrict__ g_hj,
    const float* __restrict__ Wq, const float* __restrict__ Wk,
    const float* __restrict__ Wv1, const float* __restrict__ Wpv1,
    const float* __restrict__ Wg,
    const float* __restrict__ Wek, const float* __restrict__ Wev,
    const float* __restrict__ Wo, const float* __restrict__ Wv2,
    const float* __restrict__ Wpv2,
    unsigned short* __restrict__ hi_ws, unsigned short* __restrict__ hj_ws,
    unsigned short* __restrict__ WekT, unsigned short* __restrict__ WevT,
    unsigned short* __restrict__ WoT, unsigned short* __restrict__ W2T,
    unsigned short* __restrict__ WnT)
{
    const int bx = blockIdx.x, tid = threadIdx.x;
    __shared__ unsigned short sLT[64*65];
    if (bx < 408){
        const float* src; unsigned short* dst; int W, ldD, R0, C0;
        int t = bx;
        if (t < 160){ src=Wv2;  dst=W2T;            W=SDI; ldD=DM;  R0=(t%20)*64; C0=(t/20)*64; }
        else if (t < 320){ t-=160; src=Wpv2; dst=W2T + SDI*DM; W=SDI; ldD=DM; R0=(t%20)*64; C0=(t/20)*64; }
        else if (t < 360){ t-=320; src=Wek; dst=WekT; W=SDI; ldD=DD; R0=(t%20)*64; C0=(t/20)*64; }
        else if (t < 400){ t-=360; src=Wev; dst=WevT; W=SDI; ldD=DD; R0=(t%20)*64; C0=(t/20)*64; }
        else { t-=400; src=Wo; dst=WoT; W=DD; ldD=DI; R0=(t%2)*64; C0=(t/2)*64; }
        const int tx = tid & 63, ty = tid >> 6;
        #pragma unroll
        for (int k=0;k<16;++k){
            int c = C0 + 4*k + ty;
            sLT[tx*65 + 4*k + ty] = f2bf(src[(size_t)c*W + R0 + tx]);
        }
        __syncthreads();
        #pragma unroll
        for (int k=0;k<16;++k){
            int rr = 4*k + ty;
            dst[(size_t)(R0+rr)*ldD + C0 + tx] = sLT[rr*65 + tx];
        }
    } else {
        const int node = bx - 408;
        if (tid < 64){
            float h0 = h[node*DD + tid], h1 = h[node*DD + 64 + tid];
            float s1 = h0 + h1, s2 = h0*h0 + h1*h1;
            #pragma unroll
            for (int off=32; off; off>>=1){ s1 += __shfl_xor(s1,off); s2 += __shfl_xor(s2,off); }
            float mu   = s1*(1.0f/DD);
            float var  = s2*(1.0f/DD) - mu*mu;
            float rstd = rsqrtf(var + 1e-5f);
            float c0 = (h0-mu)*rstd, c1 = (h1-mu)*rstd;
            hi_ws[node*DD + tid]      = f2bf(c0*g_hi[tid]);
            hi_ws[node*DD + 64 + tid] = f2bf(c1*g_hi[64+tid]);
            hj_ws[node*DD + tid]      = f2bf(c0*g_hj[tid]);
            hj_ws[node*DD + 64 + tid] = f2bf(c1*g_hj[64+tid]);
        }
        // WnT rows: 0..255 Wq | 256..303 Wg(40)+pad | 304..559 Wk | 560..1071 Wv1 | 1072..1583 Wpv1
        for (int f = node*256 + tid; f < 1584*DD; f += 256*256){
            int row = f >> 7, d = f & 127;
            float v;
            if (row < 256)       v = Wq[d*DI + row];
            else if (row < 304){ int c = row-256; v = (c < HS) ? Wg[d*HS + c] : 0.0f; }
            else if (row < 560)  v = Wk[d*DI + (row-304)];
            else if (row < 1072) v = Wv1[d*DM + (row-560)];
            else                 v = Wpv1[d*DM + (row-1072)];
            WnT[f] = f2bf(v);
        }
    }
}

// ---------------------------------------------------------------------------
// node_gemm: [cols 1584] x [256 nodes] = WnT @ (hi|hj)^T via MFMA.
// ---------------------------------------------------------------------------
__global__ __launch_bounds__(256,4) void node_gemm(
    const unsigned short* __restrict__ WnT,
    const unsigned short* __restrict__ hi_ws, const unsigned short* __restrict__ hj_ws,
    const float* __restrict__ bg, const float* __restrict__ bv1, const float* __restrict__ bpv1,
    float* __restrict__ q_ws, float* __restrict__ k_ws,
    float* __restrict__ g_ws, unsigned short* __restrict__ hid_ws)
{
    const int bx = blockIdx.x;
    const int tile = bx % 99, nq = bx / 99;
    const int tid = threadIdx.x, lane = tid&63, w = tid>>6;
    const int l15 = lane&15, g4 = lane>>4;
    const int ntile = nq*4 + w;
    const unsigned short* A  = WnT + (size_t)(tile*16 + l15)*DD + 8*g4;
    const unsigned short* Bp = ((tile < 19) ? hi_ws : hj_ws) + (size_t)(ntile*16 + l15)*DD + 8*g4;
    f32x4_t c = {0.f,0.f,0.f,0.f};
    #pragma unroll
    for (int ks=0; ks<4; ++ks)
        c = MFMA(*(const bf16x8_t*)(A + 32*ks), *(const bf16x8_t*)(Bp + 32*ks), c, 0,0,0);
    const int node = ntile*16 + l15;
    const int col0 = tile*16 + 4*g4;
    if (tile < 16){
        f32x4_t* dst = (f32x4_t*)(q_ws + (size_t)node*DI + col0);
        *dst = c;
    } else if (tile < 19){
        #pragma unroll
        for (int r=0;r<4;++r){
            int cc = col0 + r - 256;
            if (cc < HS) g_ws[node*HS + cc] = sigm(c[r] + bg[cc]);
        }
    } else if (tile < 35){
        f32x4_t* dst = (f32x4_t*)(k_ws + (size_t)node*DI + (col0-304));
        *dst = c;
    } else if (tile < 67){
        int cc = col0 - 560;
        float s0 = c[0]+bv1[cc], s1 = c[1]+bv1[cc+1], s2 = c[2]+bv1[cc+2], s3 = c[3]+bv1[cc+3];
        s0 *= sigm(s0); s1 *= sigm(s1); s2 *= sigm(s2); s3 *= sigm(s3);
        uint2 pkk; pkk.x = pk2(s0,s1); pkk.y = pk2(s2,s3);
        *(uint2*)(hid_ws + (size_t)node*1024 + cc) = pkk;
    } else {
        int cc = col0 - 1072;
        float s0 = c[0]+bpv1[cc], s1 = c[1]+bpv1[cc+1], s2 = c[2]+bpv1[cc+2], s3 = c[3]+bpv1[cc+3];
        s0 *= sigm(s0); s1 *= sigm(s1); s2 *= sigm(s2); s3 *= sigm(s3);
        uint2 pkk; pkk.x = pk2(s0,s1); pkk.y = pk2(s2,s3);
        *(uint2*)(hid_ws + (size_t)node*1024 + 512 + cc) = pkk;
    }
}

// ---------------------------------------------------------------------------
// v2_gemm: vpv[node][2560] = W2T @ hid^T (+bias), bf16 out.
// ---------------------------------------------------------------------------
__global__ __launch_bounds__(256,4) void v2_gemm(
    const unsigned short* __restrict__ W2T,
    const unsigned short* __restrict__ hid_ws,
    const float* __restrict__ bv2, const float* __restrict__ bpv2,
    unsigned short* __restrict__ vpv_ws)
{
    const int bx = blockIdx.x;
    const int otile = bx % 160, nq = bx / 160;
    const int tid = threadIdx.x, lane = tid&63, w = tid>>6;
    const int l15 = lane&15, g4 = lane>>4;
    const int ntile = nq*4 + w;
    const int obase = otile*16;
    const int koff = (obase < SDI) ? 0 : 512;
    const unsigned short* A  = W2T + (size_t)(obase + l15)*DM + 8*g4;
    const unsigned short* Bp = hid_ws + (size_t)(ntile*16 + l15)*1024 + koff + 8*g4;
    f32x4_t c = {0.f,0.f,0.f,0.f};
    #pragma unroll
    for (int ks=0; ks<16; ++ks)
        c = MFMA(*(const bf16x8_t*)(A + 32*ks), *(const bf16x8_t*)(Bp + 32*ks), c, 0,0,0);
    const int node = ntile*16 + l15;
    const int o0 = obase + 4*g4;
    const float* bias = (obase < SDI) ? bv2 : bpv2;
    const int ob = (obase < SDI) ? o0 : (o0 - SDI);
    float v0 = c[0]+bias[ob], v1 = c[1]+bias[ob+1], v2 = c[2]+bias[ob+2], v3 = c[3]+bias[ob+3];
    uint2 pkk; pkk.x = pk2(v0,v1); pkk.y = pk2(v2,v3);
    *(uint2*)(vpv_ws + (size_t)node*2560 + o0) = pkk;
}

// ---------------------------------------------------------------------------
// edge_mega: per node (grid 256 = 1 block/CU, 512 thr = 8 waves).
// Phases: stage T/QK -> ek GEMM -> sim -> softmax (in-block) ->
//         5x { EV GEMM -> P (LDS) -> P@Wo -> j-reductions } -> final write.
// LDS: sT @0 32KB | sQK/sP @32768 64KB | sSIM @98304 20KB | sG | sW1 | sW2 | sQ.
// ---------------------------------------------------------------------------
#define SM_T    0
#define SM_QK   32768
#define SM_SIM  98304
#define SM_G    118784
#define SM_W1   118944
#define SM_W2   120480
#define SM_Q    123040
#define SM_TOTAL 124064

__global__ __launch_bounds__(512,2) void edge_mega(
    const float* __restrict__ t_ij,
    const unsigned short* __restrict__ WekT, const unsigned short* __restrict__ WevT,
    const unsigned short* __restrict__ WoT, const unsigned short* __restrict__ vpv_ws,
    const float* __restrict__ q_ws, const float* __restrict__ k_ws,
    const float* __restrict__ g_ws,
    const float* __restrict__ r1, const float* __restrict__ r2,
    const float* __restrict__ x1, const float* __restrict__ x2,
    const float* __restrict__ h,
    float* __restrict__ out_h, float* __restrict__ out_x1, float* __restrict__ out_x2)
{
    extern __shared__ __align__(16) char sm[];
    float* sSIM = (float*)(sm + SM_SIM);
    float* sG   = (float*)(sm + SM_G);
    float* sW1  = (float*)(sm + SM_W1);
    float* sW2  = (float*)(sm + SM_W2);
    float* sQf  = (float*)(sm + SM_Q);

    const int node = blockIdx.x;
    const int b = node >> 7;
    const int tid = threadIdx.x, lane = tid&63, w = tid>>6;
    const int l15 = lane&15, g4 = lane>>4;

    // ---- stage: T (swizzled bf16), q, gates, r1, r2 ----
    {
        const int j = tid>>2, seg = tid&3;
        const float* src = t_ij + (size_t)(node*NN + j)*DD + seg*32;
        char* row = sm + j*256;
        const int swz = (j&7)<<4;
        #pragma unroll
        for (int u=0;u<8;++u){
            float4 tv = *(const float4*)(src + 4*u);
            uint2 pkk; pkk.x = pk2(tv.x,tv.y); pkk.y = pk2(tv.z,tv.w);
            *(uint2*)(row + ((2*(seg*32+4*u)) ^ swz)) = pkk;
        }
    }
    if (tid < DI) sQf[tid] = q_ws[(size_t)node*DI + tid];
    if (tid >= DI && tid < DI+HS) sG[tid-DI] = g_ws[node*HS + (tid-DI)];
    if (tid < NN*M1) sW1[tid] = r1[(size_t)node*NN*M1 + tid];
    sW2[tid] = r2[(size_t)node*NN*M2 + tid];
    if (tid < NN*M2 - 512) sW2[512+tid] = r2[(size_t)node*NN*M2 + 512 + tid];
    __syncthreads();

    // ---- QK[j, dh256] = q*k -> swizzled bf16 @SM_QK ----
    {
        const int j = tid>>2, seg = tid&3;
        const float* kr = k_ws + (size_t)(b*NN + j)*DI + seg*64;
        char* row = sm + SM_QK + j*512;
        const int swz = (j&7)<<4;
        #pragma unroll
        for (int u=0;u<16;++u){
            float4 kv = *(const float4*)(kr + 4*u);
            const float* qv = sQf + seg*64 + 4*u;
            uint2 pkk; pkk.x = pk2(kv.x*qv[0], kv.y*qv[1]); pkk.y = pk2(kv.z*qv[2], kv.w*qv[3]);
            *(uint2*)(row + ((2*(seg*64+4*u)) ^ swz)) = pkk;
        }
    }
    // Wo B-frags for this wave's d-tile (persistent across all s)
    bf16x8_t bWo[8];
    {
        const unsigned short* wr = WoT + (size_t)(w*16 + l15)*DI + 8*g4;
        #pragma unroll
        for (int ks=0;ks<8;++ks) bWo[ks] = *(const bf16x8_t*)(wr + 32*ks);
    }
    __syncthreads();

    // ---- ek GEMM -> sSIM[j, hs] ----
    #pragma unroll
    for (int jh2=0; jh2<2; ++jh2){
        bf16x8_t bT[4][4];
        #pragma unroll
        for (int jt=0;jt<4;++jt){
            const int jc = (jh2*4+jt)*16 + l15;
            const char* row = sm + jc*256;
            const int swz = (jc&7)<<4;
            #pragma unroll
            for (int ks=0;ks<4;++ks)
                bT[jt][ks] = *(const bf16x8_t*)(row + ((2*(32*ks+8*g4)) ^ swz));
        }
        for (int p5=0; p5<5; ++p5){
            const int p = w + 8*p5;                 // m-pair = one (h,s)
            const unsigned short* ap = WekT + (size_t)(2*p)*16*DD + (size_t)l15*DD + 8*g4;
            bf16x8_t a0[4], a1[4];
            #pragma unroll
            for (int ks=0;ks<4;++ks){
                a0[ks] = *(const bf16x8_t*)(ap + 32*ks);
                a1[ks] = *(const bf16x8_t*)(ap + 16*DD + 32*ks);
            }
            const int hs = (p&7)*SS + (p>>3);
            const int o0 = 32*p + 4*g4;
            const int qk0 = o0 & 255;
            #pragma unroll
            for (int jt=0;jt<4;++jt){
                f32x4_t c0 = {0.f,0.f,0.f,0.f}, c1 = {0.f,0.f,0.f,0.f};
                #pragma unroll
                for (int ks=0;ks<4;++ks){
                    c0 = MFMA(a0[ks], bT[jt][ks], c0, 0,0,0);
                    c1 = MFMA(a1[ks], bT[jt][ks], c1, 0,0,0);
                }
                const int jr = (jh2*4+jt)*16 + l15;
                const char* qrow = sm + SM_QK + jr*512;
                const int swz = (jr&7)<<4;
                uint2 u0 = *(const uint2*)(qrow + ((2*qk0) ^ swz));
                uint2 u1 = *(const uint2*)(qrow + ((2*(qk0+16)) ^ swz));
                float part =
                    (c0[0]*sigm(c0[0]))*bflo(u0.x) + (c0[1]*sigm(c0[1]))*bfhi(u0.x)
                  + (c0[2]*sigm(c0[2]))*bflo(u0.y) + (c0[3]*sigm(c0[3]))*bfhi(u0.y)
                  + (c1[0]*sigm(c1[0]))*bflo(u1.x) + (c1[1]*sigm(c1[1]))*bfhi(u1.x)
                  + (c1[2]*sigm(c1[2]))*bflo(u1.y) + (c1[3]*sigm(c1[3]))*bfhi(u1.y);
                part += __shfl_xor(part, 16);
                part += __shfl_xor(part, 32);
                if (g4 == 0) sSIM[jr*HS + hs] = part;
            }
        }
    }
    __syncthreads();

    // ---- softmax over j, gate-pre-scaled (attn *= gate) ----
    #pragma unroll
    for (int u=0; u<5; ++u){
        const int hs = w*5 + u;
        float v0 = sSIM[lane*HS + hs];
        float v1 = sSIM[(lane+64)*HS + hs];
        float m = fmaxf(v0,v1);
        #pragma unroll
        for (int off=32; off; off>>=1) m = fmaxf(m, __shfl_xor(m,off));
        float e0 = __expf(v0-m), e1 = __expf(v1-m);
        float ssum = e0+e1;
        #pragma unroll
        for (int off=32; off; off>>=1) ssum += __shfl_xor(ssum,off);
        float inv = __fdividef(sG[hs], ssum);
        sSIM[lane*HS + hs]      = e0*inv;
        sSIM[(lane+64)*HS + hs] = e1*inv;
    }
    __syncthreads();

    // ---- per-s: EV GEMM -> sP ; OUT = P@Wo -> reductions ----
    const int d = w*16 + l15;
    float ah = 0.f;
    float ax1[M1] = {0.f,0.f,0.f};
    float ax2[M2] = {0.f,0.f,0.f,0.f,0.f};

    #pragma unroll
    for (int s=0; s<SS; ++s){
        #pragma unroll
        for (int jh2=0; jh2<2; ++jh2){
            bf16x8_t bT[4][4];
            #pragma unroll
            for (int jt=0;jt<4;++jt){
                const int jc = (jh2*4+jt)*16 + l15;
                const char* row = sm + jc*256;
                const int swz = (jc&7)<<4;
                #pragma unroll
                for (int ks=0;ks<4;++ks)
                    bT[jt][ks] = *(const bf16x8_t*)(row + ((2*(32*ks+8*g4)) ^ swz));
            }
            #pragma unroll
            for (int mloc=0; mloc<2; ++mloc){
                const int mt = w*2 + mloc;
                const unsigned short* ap = WevT + (size_t)(s*DI + mt*16 + l15)*DD + 8*g4;
                bf16x8_t aa[4];
                #pragma unroll
                for (int ks=0;ks<4;++ks) aa[ks] = *(const bf16x8_t*)(ap + 32*ks);
                const int m0 = mt*16 + 4*g4;
                const int hh = mt >> 1;
                const float gtv = sG[hh*SS + s];
                #pragma unroll
                for (int jt=0;jt<4;++jt){
                    f32x4_t c = {0.f,0.f,0.f,0.f};
                    #pragma unroll
                    for (int ks=0;ks<4;++ks) c = MFMA(aa[ks], bT[jt][ks], c, 0,0,0);
                    const int jc = (jh2*4+jt)*16 + l15;
                    const float atv = sSIM[jc*HS + hh*SS + s];   // gate-scaled attn
                    const unsigned short* vb = vpv_ws + (size_t)(b*NN + jc)*2560 + s*DI + m0;
                    uint2 vv = *(const uint2*)vb;
                    uint2 pp = *(const uint2*)(vb + SDI);
                    float q0 = atv*bflo(vv.x) + gtv*c[0]*bflo(pp.x);
                    float q1 = atv*bfhi(vv.x) + gtv*c[1]*bfhi(pp.x);
                    float q2 = atv*bflo(vv.y) + gtv*c[2]*bflo(pp.y);
                    float q3 = atv*bfhi(vv.y) + gtv*c[3]*bfhi(pp.y);
                    uint2 pkk; pkk.x = pk2(q0,q1); pkk.y = pk2(q2,q3);
                    *(uint2*)(sm + SM_QK + jc*512 + ((2*m0) ^ ((jc&7)<<4))) = pkk;
                }
            }
        }
        __syncthreads();
        #pragma unroll
        for (int jt=0; jt<8; ++jt){
            const int arow = jt*16 + l15;
            const char* pb = sm + SM_QK + arow*512;
            const int aswz = (arow&7)<<4;
            f32x4_t c = {0.f,0.f,0.f,0.f};
            #pragma unroll
            for (int ks=0;ks<8;++ks){
                bf16x8_t a = *(const bf16x8_t*)(pb + ((64*ks + 16*g4) ^ aswz));
                c = MFMA(a, bWo[ks], c, 0,0,0);
            }
            if (s == 0){
                ah += c[0]+c[1]+c[2]+c[3];
            } else if (s == 1){
                #pragma unroll
                for (int r=0;r<4;++r){
                    const int jr = jt*16 + 4*g4 + r;
                    #pragma unroll
                    for (int m=0;m<M1;++m) ax1[m] = fmaf(sW1[jr*M1+m], c[r], ax1[m]);
                }
            } else if (s == 2){
                #pragma unroll
                for (int r=0;r<4;++r){
                    const int jr = jt*16 + 4*g4 + r;
                    #pragma unroll
                    for (int m=0;m<M2;++m) ax2[m] = fmaf(sW2[jr*M2+m], c[r], ax2[m]);
                }
            } else if (s == 3){
                #pragma unroll
                for (int r=0;r<4;++r){
                    const int jr = jt*16 + 4*g4 + r;
                    const float* xb = x1 + ((size_t)(b*NN + jr)*DD + d)*M1;
                    #pragma unroll
                    for (int m=0;m<M1;++m) ax1[m] = fmaf(xb[m], c[r], ax1[m]);
                }
            } else {
                #pragma unroll
                for (int r=0;r<4;++r){
                    const int jr = jt*16 + 4*g4 + r;
                    const float* xb = x2 + ((size_t)(b*NN + jr)*DD + d)*M2;
                    #pragma unroll
                    for (int m=0;m<M2;++m) ax2[m] = fmaf(xb[m], c[r], ax2[m]);
                }
            }
        }
        __syncthreads();
    }

    // ---- final reduce over g4 groups, write outputs directly ----
    {
        float v0 = ah;
        float v1 = ax1[0], v2 = ax1[1], v3 = ax1[2];
        float v4 = ax2[0], v5 = ax2[1], v6 = ax2[2], v7 = ax2[3], v8 = ax2[4];
        v0 += __shfl_xor(v0,16); v0 += __shfl_xor(v0,32);
        v1 += __shfl_xor(v1,16); v1 += __shfl_xor(v1,32);
        v2 += __shfl_xor(v2,16); v2 += __shfl_xor(v2,32);
        v3 += __shfl_xor(v3,16); v3 += __shfl_xor(v3,32);
        v4 += __shfl_xor(v4,16); v4 += __shfl_xor(v4,32);
        v5 += __shfl_xor(v5,16); v5 += __shfl_xor(v5,32);
        v6 += __shfl_xor(v6,16); v6 += __shfl_xor(v6,32);
        v7 += __shfl_xor(v7,16); v7 += __shfl_xor(v7,32);
        v8 += __shfl_xor(v8,16); v8 += __shfl_xor(v8,32);
        if (g4 == 0){
            out_h[(size_t)node*DD + d] = h[(size_t)node*DD + d] + v0;
            float* o1 = out_x1 + ((size_t)node*DD + d)*M1;
            o1[0] = v1; o1[1] = v2; o1[2] = v3;
            float* o2 = out_x2 + ((size_t)node*DD + d)*M2;
            o2[0] = v4; o2[1] = v5; o2[2] = v6; o2[3] = v7; o2[4] = v8;
        }
    }
}

// ---------------------------------------------------------------------------
extern "C" void kernel_launch(void* const* d_in, const int* in_sizes, int n_in,
                              void* d_out, int out_size, void* d_ws, size_t ws_size,
                              hipStream_t stream)
{
    (void)in_sizes; (void)n_in; (void)out_size; (void)ws_size;
    const float* h    = (const float*)d_in[0];
    const float* t_ij = (const float*)d_in[1];
    const float* r1   = (const float*)d_in[2];
    const float* r2   = (const float*)d_in[3];
    const float* x1   = (const float*)d_in[4];
    const float* x2   = (const float*)d_in[5];
    const float* g_hi = (const float*)d_in[6];
    const float* g_hj = (const float*)d_in[7];
    const float* Wq   = (const float*)d_in[8];
    const float* Wk   = (const float*)d_in[9];
    const float* Wv1  = (const float*)d_in[10];
    const float* bv1  = (const float*)d_in[11];
    const float* Wv2  = (const float*)d_in[12];
    const float* bv2  = (const float*)d_in[13];
    const float* Wpv1 = (const float*)d_in[14];
    const float* bpv1 = (const float*)d_in[15];
    const float* Wpv2 = (const float*)d_in[16];
    const float* bpv2 = (const float*)d_in[17];
    const float* Wek  = (const float*)d_in[18];
    const float* Wev  = (const float*)d_in[19];
    const float* Wg   = (const float*)d_in[20];
    const float* bg   = (const float*)d_in[21];
    const float* Wo   = (const float*)d_in[22];

    float* fb     = (float*)d_ws;
    float* q_ws   = fb;                       // 65536
    float* k_ws   = q_ws   + 65536;           // 65536
    float* g_ws   = k_ws   + 65536;           // 10240
    unsigned short* hi_ws  = (unsigned short*)(g_ws + 10240);
    unsigned short* hj_ws  = hi_ws  + 32768;
    unsigned short* hid_ws = hj_ws  + 32768;  // 262144
    unsigned short* vpv_ws = hid_ws + 262144; // 655360
    unsigned short* WekT   = vpv_ws + 655360; // 163840
    unsigned short* WevT   = WekT   + 163840; // 163840
    unsigned short* WoT    = WevT   + 163840; // 32768
    unsigned short* W2T    = WoT    + 32768;  // 1310720
    unsigned short* WnT    = W2T    + 1310720;// 202752

    float* out_h  = (float*)d_out;
    float* out_x1 = out_h  + BB*NN*DD;
    float* out_x2 = out_x1 + BB*NN*DD*M1;

    (void)hipFuncSetAttribute((const void*)edge_mega,
        hipFuncAttributeMaxDynamicSharedMemorySize, SM_TOTAL);

    prep<<<664, 256, 0, stream>>>(h, g_hi, g_hj, Wq, Wk, Wv1, Wpv1, Wg,
        Wek, Wev, Wo, Wv2, Wpv2, hi_ws, hj_ws, WekT, WevT, WoT, W2T, WnT);

    node_gemm<<<396, 256, 0, stream>>>(WnT, hi_ws, hj_ws, bg, bv1, bpv1,
        q_ws, k_ws, g_ws, hid_ws);

    v2_gemm<<<640, 256, 0, stream>>>(W2T, hid_ws, bv2, bpv2, vpv_ws);

    edge_mega<<<256, 512, SM_TOTAL, stream>>>(t_ij, WekT, WevT, WoT, vpv_ws,
        q_ws, k_ws, g_ws, r1, r2, x1, x2, h, out_h, out_x1, out_x2);
}